// Round 2
// baseline (1219.617 us; speedup 1.0000x reference)
//
#include <hip/hip_runtime.h>

#define N_NODES 65536
#define N_EDGES 1048576
#define NB      512

typedef unsigned short u16;
typedef unsigned int   u32;

__device__ __forceinline__ float bf2f(u16 u) { return __uint_as_float(((u32)u) << 16); }
__device__ __forceinline__ u16 f2bf(float f) {
    u32 u = __float_as_uint(f);
    u32 r = (u + 0x7fffu + ((u >> 16) & 1u)) >> 16;
    return (u16)r;
}
__device__ __forceinline__ float wsum(float v) {
    for (int o = 32; o; o >>= 1) v += __shfl_xor(v, o, 64);
    return v;
}
__device__ __forceinline__ float wmax(float v) {
    for (int o = 32; o; o >>= 1) v = fmaxf(v, __shfl_xor(v, o, 64));
    return v;
}

// ---------- tiny precompute: M1[j*4+h] = sum_c We1[j,h*64+c]*ae1[h,c]; M2[j] likewise ----------
__global__ void k_prep(const float* g1We, const float* g1ae, const float* g2We, const float* g2ae,
                       float* M1, float* M2) {
    int t = threadIdx.x;
    if (t < 20) {
        int j = t >> 2, h = t & 3;
        float s = 0.f;
        for (int c = 0; c < 64; c++) s += g1We[j * 256 + h * 64 + c] * g1ae[h * 64 + c];
        M1[t] = s;
    } else if (t < 25) {
        int j = t - 20;
        float s = 0.f;
        for (int c = 0; c < 64; c++) s += g2We[j * 64 + c] * g2ae[c];
        M2[j] = s;
    }
}

// ---------- scene = global_feat @ scene_W + b  (512x512x128) ----------
__global__ __launch_bounds__(256) void k_scene(const float* __restrict__ gf, const float* __restrict__ W,
                                               const float* __restrict__ bias, float* __restrict__ scene) {
    int idx = blockIdx.x * 256 + threadIdx.x;   // 65536 outputs
    int b = idx >> 7, j = idx & 127;
    float acc = 0.f;
    for (int k = 0; k < 512; k++) acc += gf[b * 512 + k] * W[k * 128 + j];
    scene[idx] = acc + bias[j];
}

// ---------- counting sort of edges by dst ----------
__global__ __launch_bounds__(256) void k_hist(const int* ei, int* cnt) {
    int e = blockIdx.x * 256 + threadIdx.x;
    atomicAdd(&cnt[ei[N_EDGES + e]], 1);
}

__global__ __launch_bounds__(1024) void k_scan(const int* cnt, int* row_ptr, int* cursor) {
    __shared__ int sd[1024];
    int t = threadIdx.x;
    int base = t * 64;
    int s = 0;
    for (int i = 0; i < 64; i++) s += cnt[base + i];
    sd[t] = s;
    __syncthreads();
    int mine = s;
    for (int off = 1; off < 1024; off <<= 1) {
        int v = (t >= off) ? sd[t - off] : 0;
        __syncthreads();
        sd[t] += v;
        __syncthreads();
    }
    int run = sd[t] - mine;   // exclusive prefix
    for (int i = 0; i < 64; i++) {
        int idx = base + i;
        row_ptr[idx] = run;
        cursor[idx] = run;
        run += cnt[idx];
    }
    if (t == 1023) row_ptr[N_NODES] = run;
}

__global__ __launch_bounds__(256) void k_scatter(const int* ei, int* cursor, int* ssrc, int* seid) {
    int e = blockIdx.x * 256 + threadIdx.x;
    int d = ei[N_EDGES + e];
    int pos = atomicAdd(&cursor[d], 1);
    ssrc[pos] = ei[e];
    seid[pos] = e;
}

// ---------- per-edge attention-edge terms ----------
__global__ __launch_bounds__(256) void k_edge_ae(const float* __restrict__ ea, const float* __restrict__ M1,
                                                 const float* __restrict__ M2,
                                                 float* __restrict__ a1e, float* __restrict__ a2e) {
    int e = blockIdx.x * 256 + threadIdx.x;
    float v[5];
    for (int j = 0; j < 5; j++) v[j] = ea[e * 5 + j];
    for (int h = 0; h < 4; h++) {
        float s = 0.f;
        for (int j = 0; j < 5; j++) s += v[j] * M1[j * 4 + h];
        a1e[e * 4 + h] = s;
    }
    float s = 0.f;
    for (int j = 0; j < 5; j++) s += v[j] * M2[j];
    a2e[e] = s;
}

// ---------- vis = relu(roi @ roiW + b)   (Nx256)@(256x64), fp32, col-half per blockIdx.y ----------
__global__ __launch_bounds__(256) void k_vis(const float* __restrict__ A, const float* __restrict__ W,
                                             const float* __restrict__ bias, float* __restrict__ out) {
    __shared__ float Wl[8192];      // 256 x 32 col-half
    __shared__ float As[8][256];
    int t = threadIdx.x, ch = blockIdx.y;
    for (int idx = t; idx < 8192; idx += 256) { int k = idx >> 5, c = idx & 31; Wl[idx] = W[k * 64 + ch * 32 + c]; }
    int r = t >> 5, c = t & 31;
    float bb = bias[ch * 32 + c];
    for (int step = 0; step < 8; step++) {
        int n0 = blockIdx.x * 64 + step * 8;
        __syncthreads();
        for (int idx = t; idx < 2048; idx += 256) As[idx >> 8][idx & 255] = A[(n0 + (idx >> 8)) * 256 + (idx & 255)];
        __syncthreads();
        float acc = 0.f;
        for (int k = 0; k < 256; k++) acc += As[r][k] * Wl[k * 32 + c];
        out[(n0 + r) * 64 + ch * 32 + c] = fmaxf(acc + bb, 0.f);
    }
}

// ---------- h2 = out1 @ g2W   (Nx256 bf16)@(256x64 fp32) -> fp32, col-half per blockIdx.y ----------
__global__ __launch_bounds__(256) void k_h2(const u16* __restrict__ A, const float* __restrict__ W,
                                            float* __restrict__ out) {
    __shared__ float Wl[8192];
    __shared__ float As[8][256];
    int t = threadIdx.x, ch = blockIdx.y;
    for (int idx = t; idx < 8192; idx += 256) { int k = idx >> 5, c = idx & 31; Wl[idx] = W[k * 64 + ch * 32 + c]; }
    int r = t >> 5, c = t & 31;
    for (int step = 0; step < 8; step++) {
        int n0 = blockIdx.x * 64 + step * 8;
        __syncthreads();
        for (int idx = t; idx < 2048; idx += 256) As[idx >> 8][idx & 255] = bf2f(A[(n0 + (idx >> 8)) * 256 + (idx & 255)]);
        __syncthreads();
        float acc = 0.f;
        for (int k = 0; k < 256; k++) acc += As[r][k] * Wl[k * 32 + c];
        out[(n0 + r) * 64 + ch * 32 + c] = acc;
    }
}

// ---------- h1 = [x | vis] @ g1_W   (Nx77)@(77x256) -> bf16, col-quarter per blockIdx.y ----------
__global__ __launch_bounds__(256) void k_h1(const float* __restrict__ x, const float* __restrict__ vis,
                                            const float* __restrict__ g1W, u16* __restrict__ h1) {
    __shared__ float Wl[4928];      // 77 x 64 col-quarter
    __shared__ float As[4][80];
    int t = threadIdx.x, ch = blockIdx.y;
    for (int idx = t; idx < 4928; idx += 256) { int k = idx >> 6, c = idx & 63; Wl[idx] = g1W[k * 256 + ch * 64 + c]; }
    int r = t >> 6, c = t & 63;
    for (int step = 0; step < 16; step++) {
        int n0 = blockIdx.x * 64 + step * 4;
        __syncthreads();
        for (int idx = t; idx < 308; idx += 256) {
            int rr = idx / 77, k = idx - rr * 77;
            As[rr][k] = (k < 13) ? x[(n0 + rr) * 13 + k] : vis[(n0 + rr) * 64 + (k - 13)];
        }
        __syncthreads();
        float acc = 0.f;
        for (int k = 0; k < 77; k++) acc += As[r][k] * Wl[k * 64 + c];
        h1[(n0 + r) * 256 + ch * 64 + c] = f2bf(acc);
    }
}

// ---------- a1_s/a1_d: per-node per-head dot(h1_row, att) ----------
__global__ __launch_bounds__(256) void k_a1(const u16* __restrict__ h1, const float* __restrict__ as_,
                                            const float* __restrict__ ad_, float* a1s, float* a1d) {
    int n = blockIdx.x, t = threadIdx.x;
    float v = bf2f(h1[n * 256 + t]);
    float ps = wsum(v * as_[t]);
    float pd = wsum(v * ad_[t]);
    if ((t & 63) == 0) {
        a1s[n * 4 + (t >> 6)] = ps;
        a1d[n * 4 + (t >> 6)] = pd;
    }
}

__global__ __launch_bounds__(256) void k_a2(const float* __restrict__ h2, const float* __restrict__ as_,
                                            const float* __restrict__ ad_, float* a2s, float* a2d) {
    int t = threadIdx.x;
    int w = t >> 6, lane = t & 63;
    int n = blockIdx.x * 4 + w;
    float v = h2[n * 64 + lane];
    float ps = wsum(v * as_[lane]);
    float pd = wsum(v * ad_[lane]);
    if (lane == 0) { a2s[n] = ps; a2d[n] = pd; }
}

// ---------- GAT1 softmax + aggregation: block per dst, wave per head ----------
__global__ __launch_bounds__(256) void k_agg1(const int* __restrict__ row_ptr, const int* __restrict__ ssrc,
                                              const int* __restrict__ seid,
                                              const float* __restrict__ a1s, const float* __restrict__ a1d,
                                              const float* __restrict__ a1e,
                                              const u16* __restrict__ h1, const float* __restrict__ bias,
                                              u16* __restrict__ out1) {
    int n = blockIdx.x, t = threadIdx.x;
    int beg = row_ptr[n], end = row_ptr[n + 1];
    int deg = end - beg;
    if (deg == 0) { out1[n * 256 + t] = f2bf(fmaxf(bias[t], 0.f)); return; }
    int h = t >> 6, lane = t & 63;
    float adn = a1d[n * 4 + h];
    float m = -3.0e38f, s = 0.f;
    for (int i = lane; i < deg; i += 64) {
        int src = ssrc[beg + i], eid = seid[beg + i];
        float l = a1s[src * 4 + h] + adn + a1e[eid * 4 + h];
        l = (l > 0.f) ? l : 0.2f * l;
        if (l > m) { s = s * __expf(m - l) + 1.f; m = l; }
        else       { s += __expf(l - m); }
    }
    for (int o = 32; o; o >>= 1) {
        float mo = __shfl_xor(m, o, 64), so = __shfl_xor(s, o, 64);
        float M = fmaxf(m, mo);
        s = s * __expf(m - M) + so * __expf(mo - M);
        m = M;
    }
    float acc = 0.f;
    for (int i = 0; i < deg; i++) {
        int src = ssrc[beg + i], eid = seid[beg + i];
        float l = a1s[src * 4 + h] + adn + a1e[eid * 4 + h];
        l = (l > 0.f) ? l : 0.2f * l;
        float wgt = __expf(l - m);
        acc += wgt * bf2f(h1[src * 256 + t]);
    }
    float o = acc / (s + 1e-16f) + bias[t];
    out1[n * 256 + t] = f2bf(fmaxf(o, 0.f));
}

// ---------- GAT2 softmax + aggregation: one wave per dst ----------
__global__ __launch_bounds__(64) void k_agg2(const int* __restrict__ row_ptr, const int* __restrict__ ssrc,
                                             const int* __restrict__ seid,
                                             const float* __restrict__ a2s, const float* __restrict__ a2d,
                                             const float* __restrict__ a2e,
                                             const float* __restrict__ h2, const float* __restrict__ bias,
                                             float* __restrict__ hfin) {
    int n = blockIdx.x, lane = threadIdx.x;
    int beg = row_ptr[n], end = row_ptr[n + 1];
    int deg = end - beg;
    if (deg == 0) { hfin[n * 64 + lane] = bias[lane]; return; }
    float adn = a2d[n];
    float m = -3.0e38f, s = 0.f;
    for (int i = lane; i < deg; i += 64) {
        int src = ssrc[beg + i], eid = seid[beg + i];
        float l = a2s[src] + adn + a2e[eid];
        l = (l > 0.f) ? l : 0.2f * l;
        if (l > m) { s = s * __expf(m - l) + 1.f; m = l; }
        else       { s += __expf(l - m); }
    }
    for (int o = 32; o; o >>= 1) {
        float mo = __shfl_xor(m, o, 64), so = __shfl_xor(s, o, 64);
        float M = fmaxf(m, mo);
        s = s * __expf(m - M) + so * __expf(mo - M);
        m = M;
    }
    float acc = 0.f;
    for (int i = 0; i < deg; i++) {
        int src = ssrc[beg + i], eid = seid[beg + i];
        float l = a2s[src] + adn + a2e[eid];
        l = (l > 0.f) ? l : 0.2f * l;
        float wgt = __expf(l - m);
        acc += wgt * h2[src * 64 + lane];
    }
    hfin[n * 64 + lane] = acc / (s + 1e-16f) + bias[lane];
}

// ---------- global-attention pooling + classifier: block (1 wave) per graph ----------
__global__ __launch_bounds__(64) void k_pool(const int* __restrict__ bvec, const float* __restrict__ hf,
                                             const float* gateW, const float* gateb,
                                             const float* __restrict__ scene,
                                             const float* c1W, const float* c1b,
                                             const float* c2W, const float* c2b,
                                             float* __restrict__ outp) {
    int b = blockIdx.x, lane = threadIdx.x;
    __shared__ float gwl[64], se[64], comb[192], hid[64];
    gwl[lane] = gateW[lane];
    __syncthreads();
    int s0, s1;
    { int lo = 0, hi = N_NODES; while (lo < hi) { int mid = (lo + hi) >> 1; if (bvec[mid] < b) lo = mid + 1; else hi = mid; } s0 = lo; }
    { int lo = 0, hi = N_NODES; while (lo < hi) { int mid = (lo + hi) >> 1; if (bvec[mid] < b + 1) lo = mid + 1; else hi = mid; } s1 = lo; }
    float gb = gateb[0];
    float m = -3.0e38f, ssum = 0.f, acc = 0.f;
    for (int cs = s0; cs < s1; cs += 64) {
        int cnt = min(64, s1 - cs);
        float l = -3.0e38f;
        if (lane < cnt) {
            int n = cs + lane;
            float d = 0.f;
            for (int i = 0; i < 64; i++) d += hf[n * 64 + i] * gwl[i];
            l = d + gb;
        }
        float cm = wmax(l);
        float newm = fmaxf(m, cm);
        float rsc = __expf(m - newm);
        float e = (lane < cnt) ? __expf(l - newm) : 0.f;
        float es = wsum(e);
        ssum = ssum * rsc + es;
        se[lane] = e;
        __syncthreads();
        float a2 = 0.f;
        for (int i = 0; i < cnt; i++) a2 += se[i] * hf[(cs + i) * 64 + lane];
        acc = acc * rsc + a2;
        __syncthreads();
        m = newm;
    }
    float rel = acc / (ssum + 1e-16f);
    comb[lane] = scene[b * 128 + lane];
    comb[64 + lane] = scene[b * 128 + 64 + lane];
    comb[128 + lane] = rel;
    __syncthreads();
    float hj = 0.f;
    for (int k = 0; k < 192; k++) hj += comb[k] * c1W[k * 64 + lane];
    hj += c1b[lane];
    hid[lane] = fmaxf(hj, 0.f);
    __syncthreads();
    if (lane < 3) {
        float o = 0.f;
        for (int k = 0; k < 64; k++) o += hid[k] * c2W[k * 3 + lane];
        o += c2b[lane];
        outp[b * 3 + lane] = o;
    }
}

extern "C" void kernel_launch(void* const* d_in, const int* in_sizes, int n_in,
                              void* d_out, int out_size, void* d_ws, size_t ws_size,
                              hipStream_t stream) {
    (void)in_sizes; (void)n_in; (void)out_size; (void)ws_size;
    const float* gf     = (const float*)d_in[0];
    const float* x      = (const float*)d_in[1];
    const float* roi    = (const float*)d_in[2];
    const int*   ei     = (const int*)d_in[3];
    const float* ea     = (const float*)d_in[4];
    const int*   bvec   = (const int*)d_in[5];
    const float* roiW   = (const float*)d_in[6];
    const float* roib   = (const float*)d_in[7];
    const float* sceneW = (const float*)d_in[8];
    const float* sceneb = (const float*)d_in[9];
    const float* g1W    = (const float*)d_in[10];
    const float* g1as   = (const float*)d_in[11];
    const float* g1ad   = (const float*)d_in[12];
    const float* g1We   = (const float*)d_in[13];
    const float* g1ae   = (const float*)d_in[14];
    const float* g1b    = (const float*)d_in[15];
    const float* g2W    = (const float*)d_in[16];
    const float* g2as   = (const float*)d_in[17];
    const float* g2ad   = (const float*)d_in[18];
    const float* g2We   = (const float*)d_in[19];
    const float* g2ae   = (const float*)d_in[20];
    const float* g2b    = (const float*)d_in[21];
    const float* gateW  = (const float*)d_in[22];
    const float* gateb  = (const float*)d_in[23];
    const float* c1W    = (const float*)d_in[24];
    const float* c1b    = (const float*)d_in[25];
    const float* c2W    = (const float*)d_in[26];
    const float* c2b    = (const float*)d_in[27];

    char* w = (char*)d_ws;
    size_t o = 0;
    auto nxt = [&](size_t bytes) -> char* {
        char* p = w + o;
        o += (bytes + 255) & ~(size_t)255;
        return p;
    };
    float* scene  = (float*)nxt((size_t)NB * 128 * 4);
    float* M1     = (float*)nxt(80);
    float* M2     = (float*)nxt(32);
    int* cnt      = (int*)nxt((size_t)N_NODES * 4);
    int* row_ptr  = (int*)nxt((size_t)(N_NODES + 1) * 4);
    int* cursor   = (int*)nxt((size_t)N_NODES * 4);
    int* ssrc     = (int*)nxt((size_t)N_EDGES * 4);
    int* seid     = (int*)nxt((size_t)N_EDGES * 4);
    float* a1e    = (float*)nxt((size_t)N_EDGES * 16);
    float* a2e    = (float*)nxt((size_t)N_EDGES * 4);
    float* vis    = (float*)nxt((size_t)N_NODES * 64 * 4);
    u16* h1       = (u16*)nxt((size_t)N_NODES * 256 * 2);
    u16* out1     = (u16*)nxt((size_t)N_NODES * 256 * 2);
    float* h2     = (float*)nxt((size_t)N_NODES * 64 * 4);
    float* hfin   = (float*)nxt((size_t)N_NODES * 64 * 4);
    float* a1s    = (float*)nxt((size_t)N_NODES * 16);
    float* a1d    = (float*)nxt((size_t)N_NODES * 16);
    float* a2s    = (float*)nxt((size_t)N_NODES * 4);
    float* a2d    = (float*)nxt((size_t)N_NODES * 4);

    hipMemsetAsync(cnt, 0, (size_t)N_NODES * 4, stream);
    k_prep<<<1, 32, 0, stream>>>(g1We, g1ae, g2We, g2ae, M1, M2);
    k_scene<<<(NB * 128) / 256, 256, 0, stream>>>(gf, sceneW, sceneb, scene);
    k_hist<<<N_EDGES / 256, 256, 0, stream>>>(ei, cnt);
    k_scan<<<1, 1024, 0, stream>>>(cnt, row_ptr, cursor);
    k_scatter<<<N_EDGES / 256, 256, 0, stream>>>(ei, cursor, ssrc, seid);
    k_edge_ae<<<N_EDGES / 256, 256, 0, stream>>>(ea, M1, M2, a1e, a2e);
    k_vis<<<dim3(N_NODES / 64, 2), 256, 0, stream>>>(roi, roiW, roib, vis);
    k_h1<<<dim3(N_NODES / 64, 4), 256, 0, stream>>>(x, vis, g1W, h1);
    k_a1<<<N_NODES, 256, 0, stream>>>(h1, g1as, g1ad, a1s, a1d);
    k_agg1<<<N_NODES, 256, 0, stream>>>(row_ptr, ssrc, seid, a1s, a1d, a1e, h1, g1b, out1);
    k_h2<<<dim3(N_NODES / 64, 2), 256, 0, stream>>>(out1, g2W, h2);
    k_a2<<<N_NODES / 4, 256, 0, stream>>>(h2, g2as, g2ad, a2s, a2d);
    k_agg2<<<N_NODES, 64, 0, stream>>>(row_ptr, ssrc, seid, a2s, a2d, a2e, h2, g2b, hfin);
    k_pool<<<NB, 64, 0, stream>>>(bvec, hfin, gateW, gateb, scene, c1W, c1b, c2W, c2b, (float*)d_out);
}

// Round 3
// 861.454 us; speedup vs baseline: 1.4158x; 1.4158x over previous
//
#include <hip/hip_runtime.h>

#define N_NODES 65536
#define N_EDGES 1048576
#define NB      512

typedef unsigned short u16;
typedef unsigned int   u32;

__device__ __forceinline__ float bf2f(u16 u) { return __uint_as_float(((u32)u) << 16); }
__device__ __forceinline__ float lo16(u32 u) { return __uint_as_float(u << 16); }
__device__ __forceinline__ float hi16(u32 u) { return __uint_as_float(u & 0xffff0000u); }
__device__ __forceinline__ u16 f2bf(float f) {
    u32 u = __float_as_uint(f);
    u32 r = (u + 0x7fffu + ((u >> 16) & 1u)) >> 16;
    return (u16)r;
}
__device__ __forceinline__ float wsum(float v) {
    for (int o = 32; o; o >>= 1) v += __shfl_xor(v, o, 64);
    return v;
}
__device__ __forceinline__ float wmax(float v) {
    for (int o = 32; o; o >>= 1) v = fmaxf(v, __shfl_xor(v, o, 64));
    return v;
}

// ---------- tiny precompute: M1[j*4+h] = sum_c We1[j,h*64+c]*ae1[h,c]; M2[j] likewise ----------
__global__ void k_prep(const float* g1We, const float* g1ae, const float* g2We, const float* g2ae,
                       float* M1, float* M2) {
    int t = threadIdx.x;
    if (t < 20) {
        int j = t >> 2, h = t & 3;
        float s = 0.f;
        for (int c = 0; c < 64; c++) s += g1We[j * 256 + h * 64 + c] * g1ae[h * 64 + c];
        M1[t] = s;
    } else if (t < 25) {
        int j = t - 20;
        float s = 0.f;
        for (int c = 0; c < 64; c++) s += g2We[j * 64 + c] * g2ae[c];
        M2[j] = s;
    }
}

// ---------- scene = global_feat @ scene_W + b  (512x512x128) ----------
__global__ __launch_bounds__(256) void k_scene(const float* __restrict__ gf, const float* __restrict__ W,
                                               const float* __restrict__ bias, float* __restrict__ scene) {
    int idx = blockIdx.x * 256 + threadIdx.x;
    int b = idx >> 7, j = idx & 127;
    float acc = 0.f;
    for (int k = 0; k < 512; k++) acc += gf[b * 512 + k] * W[k * 128 + j];
    scene[idx] = acc + bias[j];
}

// ---------- counting sort of edges by dst ----------
__global__ __launch_bounds__(256) void k_hist(const int* ei, int* cnt) {
    int e = blockIdx.x * 256 + threadIdx.x;
    atomicAdd(&cnt[ei[N_EDGES + e]], 1);
}

__global__ __launch_bounds__(1024) void k_scan(const int* cnt, int* row_ptr, int* cursor) {
    __shared__ int sd[1024];
    int t = threadIdx.x;
    int base = t * 64;
    int s = 0;
    for (int i = 0; i < 64; i++) s += cnt[base + i];
    sd[t] = s;
    __syncthreads();
    int mine = s;
    for (int off = 1; off < 1024; off <<= 1) {
        int v = (t >= off) ? sd[t - off] : 0;
        __syncthreads();
        sd[t] += v;
        __syncthreads();
    }
    int run = sd[t] - mine;
    for (int i = 0; i < 64; i++) {
        int idx = base + i;
        row_ptr[idx] = run;
        cursor[idx] = run;
        run += cnt[idx];
    }
    if (t == 1023) row_ptr[N_NODES] = run;
}

// ---------- scatter into dst-sorted order; fused per-edge attention-edge terms ----------
__global__ __launch_bounds__(256) void k_scatter(const int* __restrict__ ei, const float* __restrict__ ea,
                                                 const float* __restrict__ M1, const float* __restrict__ M2,
                                                 int* cursor, int* __restrict__ ssrc,
                                                 float* __restrict__ a1es, float* __restrict__ a2es) {
    int e = blockIdx.x * 256 + threadIdx.x;
    int d = ei[N_EDGES + e];
    int pos = atomicAdd(&cursor[d], 1);
    ssrc[pos] = ei[e];
    float v[5];
    for (int j = 0; j < 5; j++) v[j] = ea[e * 5 + j];
    for (int h = 0; h < 4; h++) {
        float s = 0.f;
        for (int j = 0; j < 5; j++) s += v[j] * M1[j * 4 + h];
        a1es[(size_t)pos * 4 + h] = s;
    }
    float s = 0.f;
    for (int j = 0; j < 5; j++) s += v[j] * M2[j];
    a2es[pos] = s;
}

// ---------- register-blocked GEMM: vis = relu(roi @ roiW + b)  (Nx256)@(256x64) fp32 ----------
__global__ __launch_bounds__(256) void k_vis(const float* __restrict__ A, const float* __restrict__ W,
                                             const float* __restrict__ bias, float* __restrict__ out) {
    __shared__ float At[64][68];
    __shared__ float Wl[64][68];
    int t = threadIdx.x;
    int n0 = blockIdx.x * 64;
    int cg = t & 15, rg = t >> 4;
    int sr = t >> 2, scs = (t & 3) * 16;
    float acc[4][4];
    for (int i = 0; i < 4; i++) for (int j = 0; j < 4; j++) acc[i][j] = 0.f;
    for (int kc = 0; kc < 4; kc++) {
        __syncthreads();
        const float* ap = A + (size_t)(n0 + sr) * 256 + kc * 64 + scs;
        float4 q0 = *(const float4*)ap, q1 = *(const float4*)(ap + 4);
        float4 q2 = *(const float4*)(ap + 8), q3 = *(const float4*)(ap + 12);
        At[scs + 0][sr] = q0.x;  At[scs + 1][sr] = q0.y;  At[scs + 2][sr] = q0.z;  At[scs + 3][sr] = q0.w;
        At[scs + 4][sr] = q1.x;  At[scs + 5][sr] = q1.y;  At[scs + 6][sr] = q1.z;  At[scs + 7][sr] = q1.w;
        At[scs + 8][sr] = q2.x;  At[scs + 9][sr] = q2.y;  At[scs + 10][sr] = q2.z; At[scs + 11][sr] = q2.w;
        At[scs + 12][sr] = q3.x; At[scs + 13][sr] = q3.y; At[scs + 14][sr] = q3.z; At[scs + 15][sr] = q3.w;
        const float* wp = W + (size_t)(kc * 64 + sr) * 64 + scs;
        *(float4*)&Wl[sr][scs + 0]  = *(const float4*)wp;
        *(float4*)&Wl[sr][scs + 4]  = *(const float4*)(wp + 4);
        *(float4*)&Wl[sr][scs + 8]  = *(const float4*)(wp + 8);
        *(float4*)&Wl[sr][scs + 12] = *(const float4*)(wp + 12);
        __syncthreads();
        for (int k = 0; k < 64; k++) {
            float4 a4 = *(const float4*)&At[k][rg * 4];
            float4 w4 = *(const float4*)&Wl[k][cg * 4];
            acc[0][0] += a4.x * w4.x; acc[0][1] += a4.x * w4.y; acc[0][2] += a4.x * w4.z; acc[0][3] += a4.x * w4.w;
            acc[1][0] += a4.y * w4.x; acc[1][1] += a4.y * w4.y; acc[1][2] += a4.y * w4.z; acc[1][3] += a4.y * w4.w;
            acc[2][0] += a4.z * w4.x; acc[2][1] += a4.z * w4.y; acc[2][2] += a4.z * w4.z; acc[2][3] += a4.z * w4.w;
            acc[3][0] += a4.w * w4.x; acc[3][1] += a4.w * w4.y; acc[3][2] += a4.w * w4.z; acc[3][3] += a4.w * w4.w;
        }
    }
    float4 bb = *(const float4*)(bias + cg * 4);
    for (int i = 0; i < 4; i++) {
        float4 o;
        o.x = fmaxf(acc[i][0] + bb.x, 0.f);
        o.y = fmaxf(acc[i][1] + bb.y, 0.f);
        o.z = fmaxf(acc[i][2] + bb.z, 0.f);
        o.w = fmaxf(acc[i][3] + bb.w, 0.f);
        *(float4*)(out + (size_t)(n0 + rg * 4 + i) * 64 + cg * 4) = o;
    }
}

// ---------- register-blocked GEMM: h2 = out1(bf16) @ g2W  (Nx256)@(256x64) -> fp32 ----------
__global__ __launch_bounds__(256) void k_h2(const u16* __restrict__ A, const float* __restrict__ W,
                                            float* __restrict__ out) {
    __shared__ float At[64][68];
    __shared__ float Wl[64][68];
    int t = threadIdx.x;
    int n0 = blockIdx.x * 64;
    int cg = t & 15, rg = t >> 4;
    int sr = t >> 2, scs = (t & 3) * 16;
    float acc[4][4];
    for (int i = 0; i < 4; i++) for (int j = 0; j < 4; j++) acc[i][j] = 0.f;
    for (int kc = 0; kc < 4; kc++) {
        __syncthreads();
        const u16* ap = A + (size_t)(n0 + sr) * 256 + kc * 64 + scs;
        uint4 u0 = *(const uint4*)ap;
        uint4 u1 = *(const uint4*)(ap + 8);
        At[scs + 0][sr] = lo16(u0.x);  At[scs + 1][sr] = hi16(u0.x);
        At[scs + 2][sr] = lo16(u0.y);  At[scs + 3][sr] = hi16(u0.y);
        At[scs + 4][sr] = lo16(u0.z);  At[scs + 5][sr] = hi16(u0.z);
        At[scs + 6][sr] = lo16(u0.w);  At[scs + 7][sr] = hi16(u0.w);
        At[scs + 8][sr] = lo16(u1.x);  At[scs + 9][sr] = hi16(u1.x);
        At[scs + 10][sr] = lo16(u1.y); At[scs + 11][sr] = hi16(u1.y);
        At[scs + 12][sr] = lo16(u1.z); At[scs + 13][sr] = hi16(u1.z);
        At[scs + 14][sr] = lo16(u1.w); At[scs + 15][sr] = hi16(u1.w);
        const float* wp = W + (size_t)(kc * 64 + sr) * 64 + scs;
        *(float4*)&Wl[sr][scs + 0]  = *(const float4*)wp;
        *(float4*)&Wl[sr][scs + 4]  = *(const float4*)(wp + 4);
        *(float4*)&Wl[sr][scs + 8]  = *(const float4*)(wp + 8);
        *(float4*)&Wl[sr][scs + 12] = *(const float4*)(wp + 12);
        __syncthreads();
        for (int k = 0; k < 64; k++) {
            float4 a4 = *(const float4*)&At[k][rg * 4];
            float4 w4 = *(const float4*)&Wl[k][cg * 4];
            acc[0][0] += a4.x * w4.x; acc[0][1] += a4.x * w4.y; acc[0][2] += a4.x * w4.z; acc[0][3] += a4.x * w4.w;
            acc[1][0] += a4.y * w4.x; acc[1][1] += a4.y * w4.y; acc[1][2] += a4.y * w4.z; acc[1][3] += a4.y * w4.w;
            acc[2][0] += a4.z * w4.x; acc[2][1] += a4.z * w4.y; acc[2][2] += a4.z * w4.z; acc[2][3] += a4.z * w4.w;
            acc[3][0] += a4.w * w4.x; acc[3][1] += a4.w * w4.y; acc[3][2] += a4.w * w4.z; acc[3][3] += a4.w * w4.w;
        }
    }
    for (int i = 0; i < 4; i++) {
        float4 o = make_float4(acc[i][0], acc[i][1], acc[i][2], acc[i][3]);
        *(float4*)(out + (size_t)(n0 + rg * 4 + i) * 64 + cg * 4) = o;
    }
}

// ---------- h1 = [x | vis] @ g1_W  (Nx77)@(77x256) -> bf16; col-half via blockIdx.y ----------
__global__ __launch_bounds__(256) void k_h1(const float* __restrict__ x, const float* __restrict__ vis,
                                            const float* __restrict__ g1W, u16* __restrict__ h1) {
    __shared__ float At[77][36];
    __shared__ float Wl[77][132];
    int t = threadIdx.x, ch = blockIdx.y;
    int n0 = blockIdx.x * 32;
    int cg = t & 31, rg = t >> 5;
    for (int idx = t; idx < 9856; idx += 256) {
        int k = idx >> 7, c = idx & 127;
        Wl[k][c] = g1W[(size_t)k * 256 + ch * 128 + c];
    }
    for (int idx = t; idx < 2464; idx += 256) {
        int r = idx / 77, k = idx - r * 77;
        At[k][r] = (k < 13) ? x[(size_t)(n0 + r) * 13 + k] : vis[(size_t)(n0 + r) * 64 + (k - 13)];
    }
    __syncthreads();
    float acc[4][4];
    for (int i = 0; i < 4; i++) for (int j = 0; j < 4; j++) acc[i][j] = 0.f;
    for (int k = 0; k < 77; k++) {
        float4 a4 = *(const float4*)&At[k][rg * 4];
        float4 w4 = *(const float4*)&Wl[k][cg * 4];
        acc[0][0] += a4.x * w4.x; acc[0][1] += a4.x * w4.y; acc[0][2] += a4.x * w4.z; acc[0][3] += a4.x * w4.w;
        acc[1][0] += a4.y * w4.x; acc[1][1] += a4.y * w4.y; acc[1][2] += a4.y * w4.z; acc[1][3] += a4.y * w4.w;
        acc[2][0] += a4.z * w4.x; acc[2][1] += a4.z * w4.y; acc[2][2] += a4.z * w4.z; acc[2][3] += a4.z * w4.w;
        acc[3][0] += a4.w * w4.x; acc[3][1] += a4.w * w4.y; acc[3][2] += a4.w * w4.z; acc[3][3] += a4.w * w4.w;
    }
    for (int i = 0; i < 4; i++) {
        uint2 pk;
        pk.x = (u32)f2bf(acc[i][0]) | ((u32)f2bf(acc[i][1]) << 16);
        pk.y = (u32)f2bf(acc[i][2]) | ((u32)f2bf(acc[i][3]) << 16);
        *(uint2*)(h1 + (size_t)(n0 + rg * 4 + i) * 256 + ch * 128 + cg * 4) = pk;
    }
}

// ---------- a1_s/a1_d: vectorized, wave handles 16 nodes ----------
__global__ __launch_bounds__(256) void k_a1(const u16* __restrict__ h1, const float* __restrict__ as_,
                                            const float* __restrict__ ad_, float* a1s, float* a1d) {
    int t = threadIdx.x;
    int w = t >> 6, L = t & 63;
    float4 as4 = *(const float4*)(as_ + 4 * L);
    float4 ad4 = *(const float4*)(ad_ + 4 * L);
    int base = (blockIdx.x * 4 + w) * 16;
    for (int j = 0; j < 16; j++) {
        int n = base + j;
        uint2 u = *((const uint2*)(h1 + (size_t)n * 256) + L);
        float v0 = lo16(u.x), v1 = hi16(u.x), v2 = lo16(u.y), v3 = hi16(u.y);
        float ps = v0 * as4.x + v1 * as4.y + v2 * as4.z + v3 * as4.w;
        float pd = v0 * ad4.x + v1 * ad4.y + v2 * ad4.z + v3 * ad4.w;
        for (int o = 1; o < 16; o <<= 1) { ps += __shfl_xor(ps, o, 64); pd += __shfl_xor(pd, o, 64); }
        if ((L & 15) == 0) {
            a1s[n * 4 + (L >> 4)] = ps;
            a1d[n * 4 + (L >> 4)] = pd;
        }
    }
}

__global__ __launch_bounds__(256) void k_a2(const float* __restrict__ h2, const float* __restrict__ as_,
                                            const float* __restrict__ ad_, float* a2s, float* a2d) {
    int t = threadIdx.x;
    int w = t >> 6, lane = t & 63;
    int n = blockIdx.x * 4 + w;
    float v = h2[(size_t)n * 64 + lane];
    float ps = wsum(v * as_[lane]);
    float pd = wsum(v * ad_[lane]);
    if (lane == 0) { a2s[n] = ps; a2d[n] = pd; }
}

// ---------- GAT1 softmax: per (node, head) wave -> normalized per-edge weights ----------
__global__ __launch_bounds__(256) void k_soft1(const int* __restrict__ row_ptr, const int* __restrict__ ssrc,
                                               const float* __restrict__ a1s, const float* __restrict__ a1d,
                                               const float* __restrict__ a1es, float* __restrict__ w1) {
    int n = blockIdx.x, t = threadIdx.x;
    int h = t >> 6, L = t & 63;
    int beg = row_ptr[n], deg = row_ptr[n + 1] - beg;
    if (deg == 0) return;
    float adn = a1d[n * 4 + h];
    float m = -3.0e38f, s = 0.f;
    for (int i = L; i < deg; i += 64) {
        int pos = beg + i;
        float l = a1s[ssrc[pos] * 4 + h] + adn + a1es[(size_t)pos * 4 + h];
        l = (l > 0.f) ? l : 0.2f * l;
        if (l > m) { s = s * __expf(m - l) + 1.f; m = l; }
        else       { s += __expf(l - m); }
    }
    for (int o = 32; o; o >>= 1) {
        float mo = __shfl_xor(m, o, 64), so = __shfl_xor(s, o, 64);
        float M = fmaxf(m, mo);
        s = s * __expf(m - M) + so * __expf(mo - M);
        m = M;
    }
    float inv = 1.f / (s + 1e-16f);
    for (int i = L; i < deg; i += 64) {
        int pos = beg + i;
        float l = a1s[ssrc[pos] * 4 + h] + adn + a1es[(size_t)pos * 4 + h];
        l = (l > 0.f) ? l : 0.2f * l;
        w1[(size_t)pos * 4 + h] = __expf(l - m) * inv;
    }
}

// ---------- GAT1 gather: wave per node, lane = 4 channels ----------
__global__ __launch_bounds__(256) void k_gath1(const int* __restrict__ row_ptr, const int* __restrict__ ssrc,
                                               const float* __restrict__ w1, const u16* __restrict__ h1,
                                               const float* __restrict__ bias, u16* __restrict__ out1) {
    int t = threadIdx.x;
    int wv = t >> 6, L = t & 63;
    int n = blockIdx.x * 4 + wv;
    int beg = row_ptr[n], deg = row_ptr[n + 1] - beg;
    int hd = L >> 4;
    float a0 = 0.f, a1v = 0.f, a2v = 0.f, a3v = 0.f;
    int i = 0;
    for (; i + 2 <= deg; i += 2) {
        int p0 = beg + i, p1 = p0 + 1;
        int s0 = ssrc[p0], s1 = ssrc[p1];
        float wa = w1[(size_t)p0 * 4 + hd];
        float wb = w1[(size_t)p1 * 4 + hd];
        uint2 ua = *((const uint2*)(h1 + (size_t)s0 * 256) + L);
        uint2 ub = *((const uint2*)(h1 + (size_t)s1 * 256) + L);
        a0 += wa * lo16(ua.x) + wb * lo16(ub.x);
        a1v += wa * hi16(ua.x) + wb * hi16(ub.x);
        a2v += wa * lo16(ua.y) + wb * lo16(ub.y);
        a3v += wa * hi16(ua.y) + wb * hi16(ub.y);
    }
    if (i < deg) {
        int p0 = beg + i;
        int s0 = ssrc[p0];
        float wa = w1[(size_t)p0 * 4 + hd];
        uint2 ua = *((const uint2*)(h1 + (size_t)s0 * 256) + L);
        a0 += wa * lo16(ua.x); a1v += wa * hi16(ua.x);
        a2v += wa * lo16(ua.y); a3v += wa * hi16(ua.y);
    }
    float4 bb = *(const float4*)(bias + 4 * L);
    uint2 pk;
    pk.x = (u32)f2bf(fmaxf(a0 + bb.x, 0.f)) | ((u32)f2bf(fmaxf(a1v + bb.y, 0.f)) << 16);
    pk.y = (u32)f2bf(fmaxf(a2v + bb.z, 0.f)) | ((u32)f2bf(fmaxf(a3v + bb.w, 0.f)) << 16);
    *((uint2*)(out1 + (size_t)n * 256) + L) = pk;
}

// ---------- GAT2 softmax: wave per node ----------
__global__ __launch_bounds__(256) void k_soft2(const int* __restrict__ row_ptr, const int* __restrict__ ssrc,
                                               const float* __restrict__ a2s, const float* __restrict__ a2d,
                                               const float* __restrict__ a2es, float* __restrict__ w2) {
    int t = threadIdx.x;
    int wv = t >> 6, L = t & 63;
    int n = blockIdx.x * 4 + wv;
    int beg = row_ptr[n], deg = row_ptr[n + 1] - beg;
    if (deg == 0) return;
    float adn = a2d[n];
    float m = -3.0e38f, s = 0.f;
    for (int i = L; i < deg; i += 64) {
        int pos = beg + i;
        float l = a2s[ssrc[pos]] + adn + a2es[pos];
        l = (l > 0.f) ? l : 0.2f * l;
        if (l > m) { s = s * __expf(m - l) + 1.f; m = l; }
        else       { s += __expf(l - m); }
    }
    for (int o = 32; o; o >>= 1) {
        float mo = __shfl_xor(m, o, 64), so = __shfl_xor(s, o, 64);
        float M = fmaxf(m, mo);
        s = s * __expf(m - M) + so * __expf(mo - M);
        m = M;
    }
    float inv = 1.f / (s + 1e-16f);
    for (int i = L; i < deg; i += 64) {
        int pos = beg + i;
        float l = a2s[ssrc[pos]] + adn + a2es[pos];
        l = (l > 0.f) ? l : 0.2f * l;
        w2[pos] = __expf(l - m) * inv;
    }
}

// ---------- GAT2 gather: wave per node, lane = channel ----------
__global__ __launch_bounds__(256) void k_gath2(const int* __restrict__ row_ptr, const int* __restrict__ ssrc,
                                               const float* __restrict__ w2, const float* __restrict__ h2,
                                               const float* __restrict__ bias, float* __restrict__ hfin) {
    int t = threadIdx.x;
    int wv = t >> 6, L = t & 63;
    int n = blockIdx.x * 4 + wv;
    int beg = row_ptr[n], deg = row_ptr[n + 1] - beg;
    float acc = 0.f;
    int i = 0;
    for (; i + 2 <= deg; i += 2) {
        int p0 = beg + i, p1 = p0 + 1;
        int s0 = ssrc[p0], s1 = ssrc[p1];
        float wa = w2[p0], wb = w2[p1];
        float va = h2[(size_t)s0 * 64 + L];
        float vb = h2[(size_t)s1 * 64 + L];
        acc += wa * va + wb * vb;
    }
    if (i < deg) {
        int p0 = beg + i;
        acc += w2[p0] * h2[(size_t)ssrc[p0] * 64 + L];
    }
    hfin[(size_t)n * 64 + L] = acc + bias[L];
}

// ---------- global-attention pooling + classifier: block (1 wave) per graph ----------
__global__ __launch_bounds__(64) void k_pool(const int* __restrict__ bvec, const float* __restrict__ hf,
                                             const float* gateW, const float* gateb,
                                             const float* __restrict__ scene,
                                             const float* c1W, const float* c1b,
                                             const float* c2W, const float* c2b,
                                             float* __restrict__ outp) {
    int b = blockIdx.x, lane = threadIdx.x;
    __shared__ float gwl[64], se[64], comb[192], hid[64];
    gwl[lane] = gateW[lane];
    __syncthreads();
    int s0, s1;
    { int lo = 0, hi = N_NODES; while (lo < hi) { int mid = (lo + hi) >> 1; if (bvec[mid] < b) lo = mid + 1; else hi = mid; } s0 = lo; }
    { int lo = 0, hi = N_NODES; while (lo < hi) { int mid = (lo + hi) >> 1; if (bvec[mid] < b + 1) lo = mid + 1; else hi = mid; } s1 = lo; }
    float gb = gateb[0];
    float m = -3.0e38f, ssum = 0.f, acc = 0.f;
    for (int cs = s0; cs < s1; cs += 64) {
        int cnt = min(64, s1 - cs);
        float l = -3.0e38f;
        if (lane < cnt) {
            int n = cs + lane;
            float d = 0.f;
            for (int i = 0; i < 64; i++) d += hf[(size_t)n * 64 + i] * gwl[i];
            l = d + gb;
        }
        float cm = wmax(l);
        float newm = fmaxf(m, cm);
        float rsc = __expf(m - newm);
        float e = (lane < cnt) ? __expf(l - newm) : 0.f;
        float es = wsum(e);
        ssum = ssum * rsc + es;
        se[lane] = e;
        __syncthreads();
        float a2 = 0.f;
        for (int i = 0; i < cnt; i++) a2 += se[i] * hf[(size_t)(cs + i) * 64 + lane];
        acc = acc * rsc + a2;
        __syncthreads();
        m = newm;
    }
    float rel = acc / (ssum + 1e-16f);
    comb[lane] = scene[b * 128 + lane];
    comb[64 + lane] = scene[b * 128 + 64 + lane];
    comb[128 + lane] = rel;
    __syncthreads();
    float hj = 0.f;
    for (int k = 0; k < 192; k++) hj += comb[k] * c1W[k * 64 + lane];
    hj += c1b[lane];
    hid[lane] = fmaxf(hj, 0.f);
    __syncthreads();
    if (lane < 3) {
        float o = 0.f;
        for (int k = 0; k < 64; k++) o += hid[k] * c2W[k * 3 + lane];
        o += c2b[lane];
        outp[b * 3 + lane] = o;
    }
}

extern "C" void kernel_launch(void* const* d_in, const int* in_sizes, int n_in,
                              void* d_out, int out_size, void* d_ws, size_t ws_size,
                              hipStream_t stream) {
    (void)in_sizes; (void)n_in; (void)out_size; (void)ws_size;
    const float* gf     = (const float*)d_in[0];
    const float* x      = (const float*)d_in[1];
    const float* roi    = (const float*)d_in[2];
    const int*   ei     = (const int*)d_in[3];
    const float* ea     = (const float*)d_in[4];
    const int*   bvec   = (const int*)d_in[5];
    const float* roiW   = (const float*)d_in[6];
    const float* roib   = (const float*)d_in[7];
    const float* sceneW = (const float*)d_in[8];
    const float* sceneb = (const float*)d_in[9];
    const float* g1W    = (const float*)d_in[10];
    const float* g1as   = (const float*)d_in[11];
    const float* g1ad   = (const float*)d_in[12];
    const float* g1We   = (const float*)d_in[13];
    const float* g1ae   = (const float*)d_in[14];
    const float* g1b    = (const float*)d_in[15];
    const float* g2W    = (const float*)d_in[16];
    const float* g2as   = (const float*)d_in[17];
    const float* g2ad   = (const float*)d_in[18];
    const float* g2We   = (const float*)d_in[19];
    const float* g2ae   = (const float*)d_in[20];
    const float* g2b    = (const float*)d_in[21];
    const float* gateW  = (const float*)d_in[22];
    const float* gateb  = (const float*)d_in[23];
    const float* c1W    = (const float*)d_in[24];
    const float* c1b    = (const float*)d_in[25];
    const float* c2W    = (const float*)d_in[26];
    const float* c2b    = (const float*)d_in[27];

    char* w = (char*)d_ws;
    size_t o = 0;
    auto nxt = [&](size_t bytes) -> char* {
        char* p = w + o;
        o += (bytes + 255) & ~(size_t)255;
        return p;
    };
    float* scene  = (float*)nxt((size_t)NB * 128 * 4);
    float* M1     = (float*)nxt(80);
    float* M2     = (float*)nxt(32);
    int* cnt      = (int*)nxt((size_t)N_NODES * 4);
    int* row_ptr  = (int*)nxt((size_t)(N_NODES + 1) * 4);
    int* cursor   = (int*)nxt((size_t)N_NODES * 4);
    int* ssrc     = (int*)nxt((size_t)N_EDGES * 4);
    float* a1es   = (float*)nxt((size_t)N_EDGES * 16);
    float* a2es   = (float*)nxt((size_t)N_EDGES * 4);
    float* visbuf = (float*)nxt((size_t)N_NODES * 64 * 4);   // vis, later aliased as w2
    u16* h1       = (u16*)nxt((size_t)N_NODES * 256 * 2);
    u16* out1     = (u16*)nxt((size_t)N_NODES * 256 * 2);
    float* w1buf  = (float*)nxt((size_t)N_EDGES * 16);       // w1, later aliased as h2
    float* hfin   = (float*)nxt((size_t)N_NODES * 64 * 4);
    float* a1s    = (float*)nxt((size_t)N_NODES * 16);
    float* a1d    = (float*)nxt((size_t)N_NODES * 16);
    float* a2s    = (float*)nxt((size_t)N_NODES * 4);
    float* a2d    = (float*)nxt((size_t)N_NODES * 4);

    float* vis = visbuf;
    float* w2  = visbuf;      // vis dead after k_h1; w2 written by k_soft2 (later)
    float* w1  = w1buf;
    float* h2  = w1buf;       // w1 dead after k_gath1; h2 written by k_h2 (later)

    hipMemsetAsync(cnt, 0, (size_t)N_NODES * 4, stream);
    k_prep<<<1, 32, 0, stream>>>(g1We, g1ae, g2We, g2ae, M1, M2);
    k_scene<<<(NB * 128) / 256, 256, 0, stream>>>(gf, sceneW, sceneb, scene);
    k_hist<<<N_EDGES / 256, 256, 0, stream>>>(ei, cnt);
    k_scan<<<1, 1024, 0, stream>>>(cnt, row_ptr, cursor);
    k_scatter<<<N_EDGES / 256, 256, 0, stream>>>(ei, ea, M1, M2, cursor, ssrc, a1es, a2es);
    k_vis<<<N_NODES / 64, 256, 0, stream>>>(roi, roiW, roib, vis);
    k_h1<<<dim3(N_NODES / 32, 2), 256, 0, stream>>>(x, vis, g1W, h1);
    k_a1<<<N_NODES / 64, 256, 0, stream>>>(h1, g1as, g1ad, a1s, a1d);
    k_soft1<<<N_NODES, 256, 0, stream>>>(row_ptr, ssrc, a1s, a1d, a1es, w1);
    k_gath1<<<N_NODES / 4, 256, 0, stream>>>(row_ptr, ssrc, w1, h1, g1b, out1);
    k_h2<<<N_NODES / 64, 256, 0, stream>>>(out1, g2W, h2);
    k_a2<<<N_NODES / 4, 256, 0, stream>>>(h2, g2as, g2ad, a2s, a2d);
    k_soft2<<<N_NODES / 4, 256, 0, stream>>>(row_ptr, ssrc, a2s, a2d, a2es, w2);
    k_gath2<<<N_NODES / 4, 256, 0, stream>>>(row_ptr, ssrc, w2, h2, g2b, hfin);
    k_pool<<<NB, 64, 0, stream>>>(bvec, hfin, gateW, gateb, scene, c1W, c1b, c2W, c2b, (float*)d_out);
}

// Round 4
// 745.016 us; speedup vs baseline: 1.6370x; 1.1563x over previous
//
#include <hip/hip_runtime.h>

#define N_NODES 65536
#define N_EDGES 1048576
#define NB      512

typedef unsigned short u16;
typedef unsigned int   u32;

__device__ __forceinline__ float bf2f(u16 u) { return __uint_as_float(((u32)u) << 16); }
__device__ __forceinline__ float lo16(u32 u) { return __uint_as_float(u << 16); }
__device__ __forceinline__ float hi16(u32 u) { return __uint_as_float(u & 0xffff0000u); }
__device__ __forceinline__ u16 f2bf(float f) {
    u32 u = __float_as_uint(f);
    u32 r = (u + 0x7fffu + ((u >> 16) & 1u)) >> 16;
    return (u16)r;
}
__device__ __forceinline__ float wsum(float v) {
    for (int o = 32; o; o >>= 1) v += __shfl_xor(v, o, 64);
    return v;
}
__device__ __forceinline__ float wmax(float v) {
    for (int o = 32; o; o >>= 1) v = fmaxf(v, __shfl_xor(v, o, 64));
    return v;
}

// ---------- tiny precompute: M1[j*4+h] = sum_c We1[j,h*64+c]*ae1[h,c]; M2[j] likewise ----------
__global__ void k_prep(const float* g1We, const float* g1ae, const float* g2We, const float* g2ae,
                       float* M1, float* M2) {
    int t = threadIdx.x;
    if (t < 20) {
        int j = t >> 2, h = t & 3;
        float s = 0.f;
        for (int c = 0; c < 64; c++) s += g1We[j * 256 + h * 64 + c] * g1ae[h * 64 + c];
        M1[t] = s;
    } else if (t < 25) {
        int j = t - 20;
        float s = 0.f;
        for (int c = 0; c < 64; c++) s += g2We[j * 64 + c] * g2ae[c];
        M2[j] = s;
    }
}

// ---------- scene = global_feat @ scene_W + b  (512x512x128) ----------
__global__ __launch_bounds__(256) void k_scene(const float* __restrict__ gf, const float* __restrict__ W,
                                               const float* __restrict__ bias, float* __restrict__ scene) {
    int idx = blockIdx.x * 256 + threadIdx.x;
    int b = idx >> 7, j = idx & 127;
    float acc = 0.f;
    for (int k = 0; k < 512; k++) acc += gf[b * 512 + k] * W[k * 128 + j];
    scene[idx] = acc + bias[j];
}

// ---------- counting sort of edges by dst ----------
__global__ __launch_bounds__(256) void k_hist(const int* ei, int* cnt) {
    int e = blockIdx.x * 256 + threadIdx.x;
    atomicAdd(&cnt[ei[N_EDGES + e]], 1);
}

// ---------- hierarchical exclusive scan of cnt[65536] ----------
// stage 1: 64 blocks x 256 threads, 4 elements/thread
__global__ __launch_bounds__(256) void k_scan_blk(const int* __restrict__ cnt, int* __restrict__ pre,
                                                  int* __restrict__ bsum) {
    __shared__ int sd[256];
    int t = threadIdx.x, b = blockIdx.x;
    int base = b * 1024 + t * 4;
    int4 c = *(const int4*)(cnt + base);
    int s = c.x + c.y + c.z + c.w;
    sd[t] = s;
    __syncthreads();
    for (int off = 1; off < 256; off <<= 1) {
        int v = (t >= off) ? sd[t - off] : 0;
        __syncthreads();
        sd[t] += v;
        __syncthreads();
    }
    int excl = sd[t] - s;
    int4 p;
    p.x = excl;
    p.y = excl + c.x;
    p.z = excl + c.x + c.y;
    p.w = excl + c.x + c.y + c.z;
    *(int4*)(pre + base) = p;
    if (t == 255) bsum[b] = sd[255];
}

// stage 2: one wave scans the 64 block sums -> exclusive
__global__ __launch_bounds__(64) void k_scan_top(int* bsum) {
    int t = threadIdx.x;
    int v = bsum[t];
    int inc = v;
    for (int off = 1; off < 64; off <<= 1) {
        int u = __shfl_up(inc, off, 64);
        if (t >= off) inc += u;
    }
    bsum[t] = inc - v;
}

// stage 3: add block offsets, produce row_ptr + cursor
__global__ __launch_bounds__(256) void k_scan_fix(const int* __restrict__ pre, const int* __restrict__ bsum,
                                                  int* __restrict__ row_ptr, int* __restrict__ cursor) {
    int i = blockIdx.x * 256 + threadIdx.x;
    int v = pre[i] + bsum[i >> 10];
    row_ptr[i] = v;
    cursor[i] = v;
    if (i == 0) row_ptr[N_NODES] = N_EDGES;
}

// ---------- scatter into dst-sorted order; fused per-edge attention-edge terms ----------
__global__ __launch_bounds__(256) void k_scatter(const int* __restrict__ ei, const float* __restrict__ ea,
                                                 const float* __restrict__ M1, const float* __restrict__ M2,
                                                 int* cursor, int* __restrict__ ssrc,
                                                 float* __restrict__ a1es, float* __restrict__ a2es) {
    int e = blockIdx.x * 256 + threadIdx.x;
    int d = ei[N_EDGES + e];
    int pos = atomicAdd(&cursor[d], 1);
    ssrc[pos] = ei[e];
    float v[5];
    for (int j = 0; j < 5; j++) v[j] = ea[e * 5 + j];
    for (int h = 0; h < 4; h++) {
        float s = 0.f;
        for (int j = 0; j < 5; j++) s += v[j] * M1[j * 4 + h];
        a1es[(size_t)pos * 4 + h] = s;
    }
    float s = 0.f;
    for (int j = 0; j < 5; j++) s += v[j] * M2[j];
    a2es[pos] = s;
}

// ---------- register-blocked GEMM: vis = relu(roi @ roiW + b)  (Nx256)@(256x64) fp32 ----------
__global__ __launch_bounds__(256) void k_vis(const float* __restrict__ A, const float* __restrict__ W,
                                             const float* __restrict__ bias, float* __restrict__ out) {
    __shared__ float At[64][68];
    __shared__ float Wl[64][68];
    int t = threadIdx.x;
    int n0 = blockIdx.x * 64;
    int cg = t & 15, rg = t >> 4;
    int sr = t >> 2, scs = (t & 3) * 16;
    float acc[4][4];
    for (int i = 0; i < 4; i++) for (int j = 0; j < 4; j++) acc[i][j] = 0.f;
    for (int kc = 0; kc < 4; kc++) {
        __syncthreads();
        const float* ap = A + (size_t)(n0 + sr) * 256 + kc * 64 + scs;
        float4 q0 = *(const float4*)ap, q1 = *(const float4*)(ap + 4);
        float4 q2 = *(const float4*)(ap + 8), q3 = *(const float4*)(ap + 12);
        At[scs + 0][sr] = q0.x;  At[scs + 1][sr] = q0.y;  At[scs + 2][sr] = q0.z;  At[scs + 3][sr] = q0.w;
        At[scs + 4][sr] = q1.x;  At[scs + 5][sr] = q1.y;  At[scs + 6][sr] = q1.z;  At[scs + 7][sr] = q1.w;
        At[scs + 8][sr] = q2.x;  At[scs + 9][sr] = q2.y;  At[scs + 10][sr] = q2.z; At[scs + 11][sr] = q2.w;
        At[scs + 12][sr] = q3.x; At[scs + 13][sr] = q3.y; At[scs + 14][sr] = q3.z; At[scs + 15][sr] = q3.w;
        const float* wp = W + (size_t)(kc * 64 + sr) * 64 + scs;
        *(float4*)&Wl[sr][scs + 0]  = *(const float4*)wp;
        *(float4*)&Wl[sr][scs + 4]  = *(const float4*)(wp + 4);
        *(float4*)&Wl[sr][scs + 8]  = *(const float4*)(wp + 8);
        *(float4*)&Wl[sr][scs + 12] = *(const float4*)(wp + 12);
        __syncthreads();
        for (int k = 0; k < 64; k++) {
            float4 a4 = *(const float4*)&At[k][rg * 4];
            float4 w4 = *(const float4*)&Wl[k][cg * 4];
            acc[0][0] += a4.x * w4.x; acc[0][1] += a4.x * w4.y; acc[0][2] += a4.x * w4.z; acc[0][3] += a4.x * w4.w;
            acc[1][0] += a4.y * w4.x; acc[1][1] += a4.y * w4.y; acc[1][2] += a4.y * w4.z; acc[1][3] += a4.y * w4.w;
            acc[2][0] += a4.z * w4.x; acc[2][1] += a4.z * w4.y; acc[2][2] += a4.z * w4.z; acc[2][3] += a4.z * w4.w;
            acc[3][0] += a4.w * w4.x; acc[3][1] += a4.w * w4.y; acc[3][2] += a4.w * w4.z; acc[3][3] += a4.w * w4.w;
        }
    }
    float4 bb = *(const float4*)(bias + cg * 4);
    for (int i = 0; i < 4; i++) {
        float4 o;
        o.x = fmaxf(acc[i][0] + bb.x, 0.f);
        o.y = fmaxf(acc[i][1] + bb.y, 0.f);
        o.z = fmaxf(acc[i][2] + bb.z, 0.f);
        o.w = fmaxf(acc[i][3] + bb.w, 0.f);
        *(float4*)(out + (size_t)(n0 + rg * 4 + i) * 64 + cg * 4) = o;
    }
}

// ---------- register-blocked GEMM: h2 = out1(bf16) @ g2W  (Nx256)@(256x64) -> fp32 ----------
__global__ __launch_bounds__(256) void k_h2(const u16* __restrict__ A, const float* __restrict__ W,
                                            float* __restrict__ out) {
    __shared__ float At[64][68];
    __shared__ float Wl[64][68];
    int t = threadIdx.x;
    int n0 = blockIdx.x * 64;
    int cg = t & 15, rg = t >> 4;
    int sr = t >> 2, scs = (t & 3) * 16;
    float acc[4][4];
    for (int i = 0; i < 4; i++) for (int j = 0; j < 4; j++) acc[i][j] = 0.f;
    for (int kc = 0; kc < 4; kc++) {
        __syncthreads();
        const u16* ap = A + (size_t)(n0 + sr) * 256 + kc * 64 + scs;
        uint4 u0 = *(const uint4*)ap;
        uint4 u1 = *(const uint4*)(ap + 8);
        At[scs + 0][sr] = lo16(u0.x);  At[scs + 1][sr] = hi16(u0.x);
        At[scs + 2][sr] = lo16(u0.y);  At[scs + 3][sr] = hi16(u0.y);
        At[scs + 4][sr] = lo16(u0.z);  At[scs + 5][sr] = hi16(u0.z);
        At[scs + 6][sr] = lo16(u0.w);  At[scs + 7][sr] = hi16(u0.w);
        At[scs + 8][sr] = lo16(u1.x);  At[scs + 9][sr] = hi16(u1.x);
        At[scs + 10][sr] = lo16(u1.y); At[scs + 11][sr] = hi16(u1.y);
        At[scs + 12][sr] = lo16(u1.z); At[scs + 13][sr] = hi16(u1.z);
        At[scs + 14][sr] = lo16(u1.w); At[scs + 15][sr] = hi16(u1.w);
        const float* wp = W + (size_t)(kc * 64 + sr) * 64 + scs;
        *(float4*)&Wl[sr][scs + 0]  = *(const float4*)wp;
        *(float4*)&Wl[sr][scs + 4]  = *(const float4*)(wp + 4);
        *(float4*)&Wl[sr][scs + 8]  = *(const float4*)(wp + 8);
        *(float4*)&Wl[sr][scs + 12] = *(const float4*)(wp + 12);
        __syncthreads();
        for (int k = 0; k < 64; k++) {
            float4 a4 = *(const float4*)&At[k][rg * 4];
            float4 w4 = *(const float4*)&Wl[k][cg * 4];
            acc[0][0] += a4.x * w4.x; acc[0][1] += a4.x * w4.y; acc[0][2] += a4.x * w4.z; acc[0][3] += a4.x * w4.w;
            acc[1][0] += a4.y * w4.x; acc[1][1] += a4.y * w4.y; acc[1][2] += a4.y * w4.z; acc[1][3] += a4.y * w4.w;
            acc[2][0] += a4.z * w4.x; acc[2][1] += a4.z * w4.y; acc[2][2] += a4.z * w4.z; acc[2][3] += a4.z * w4.w;
            acc[3][0] += a4.w * w4.x; acc[3][1] += a4.w * w4.y; acc[3][2] += a4.w * w4.z; acc[3][3] += a4.w * w4.w;
        }
    }
    for (int i = 0; i < 4; i++) {
        float4 o = make_float4(acc[i][0], acc[i][1], acc[i][2], acc[i][3]);
        *(float4*)(out + (size_t)(n0 + rg * 4 + i) * 64 + cg * 4) = o;
    }
}

// ---------- h1 = [x | vis] @ g1_W  (Nx77)@(77x256) -> bf16; col-half via blockIdx.y ----------
__global__ __launch_bounds__(256) void k_h1(const float* __restrict__ x, const float* __restrict__ vis,
                                            const float* __restrict__ g1W, u16* __restrict__ h1) {
    __shared__ float At[77][36];
    __shared__ float Wl[77][132];
    int t = threadIdx.x, ch = blockIdx.y;
    int n0 = blockIdx.x * 32;
    int cg = t & 31, rg = t >> 5;
    for (int idx = t; idx < 9856; idx += 256) {
        int k = idx >> 7, c = idx & 127;
        Wl[k][c] = g1W[(size_t)k * 256 + ch * 128 + c];
    }
    for (int idx = t; idx < 2464; idx += 256) {
        int r = idx / 77, k = idx - r * 77;
        At[k][r] = (k < 13) ? x[(size_t)(n0 + r) * 13 + k] : vis[(size_t)(n0 + r) * 64 + (k - 13)];
    }
    __syncthreads();
    float acc[4][4];
    for (int i = 0; i < 4; i++) for (int j = 0; j < 4; j++) acc[i][j] = 0.f;
    for (int k = 0; k < 77; k++) {
        float4 a4 = *(const float4*)&At[k][rg * 4];
        float4 w4 = *(const float4*)&Wl[k][cg * 4];
        acc[0][0] += a4.x * w4.x; acc[0][1] += a4.x * w4.y; acc[0][2] += a4.x * w4.z; acc[0][3] += a4.x * w4.w;
        acc[1][0] += a4.y * w4.x; acc[1][1] += a4.y * w4.y; acc[1][2] += a4.y * w4.z; acc[1][3] += a4.y * w4.w;
        acc[2][0] += a4.z * w4.x; acc[2][1] += a4.z * w4.y; acc[2][2] += a4.z * w4.z; acc[2][3] += a4.z * w4.w;
        acc[3][0] += a4.w * w4.x; acc[3][1] += a4.w * w4.y; acc[3][2] += a4.w * w4.z; acc[3][3] += a4.w * w4.w;
    }
    for (int i = 0; i < 4; i++) {
        uint2 pk;
        pk.x = (u32)f2bf(acc[i][0]) | ((u32)f2bf(acc[i][1]) << 16);
        pk.y = (u32)f2bf(acc[i][2]) | ((u32)f2bf(acc[i][3]) << 16);
        *(uint2*)(h1 + (size_t)(n0 + rg * 4 + i) * 256 + ch * 128 + cg * 4) = pk;
    }
}

// ---------- a1_s/a1_d: vectorized, wave handles 16 nodes ----------
__global__ __launch_bounds__(256) void k_a1(const u16* __restrict__ h1, const float* __restrict__ as_,
                                            const float* __restrict__ ad_, float* a1s, float* a1d) {
    int t = threadIdx.x;
    int w = t >> 6, L = t & 63;
    float4 as4 = *(const float4*)(as_ + 4 * L);
    float4 ad4 = *(const float4*)(ad_ + 4 * L);
    int base = (blockIdx.x * 4 + w) * 16;
    for (int j = 0; j < 16; j++) {
        int n = base + j;
        uint2 u = *((const uint2*)(h1 + (size_t)n * 256) + L);
        float v0 = lo16(u.x), v1 = hi16(u.x), v2 = lo16(u.y), v3 = hi16(u.y);
        float ps = v0 * as4.x + v1 * as4.y + v2 * as4.z + v3 * as4.w;
        float pd = v0 * ad4.x + v1 * ad4.y + v2 * ad4.z + v3 * ad4.w;
        for (int o = 1; o < 16; o <<= 1) { ps += __shfl_xor(ps, o, 64); pd += __shfl_xor(pd, o, 64); }
        if ((L & 15) == 0) {
            a1s[n * 4 + (L >> 4)] = ps;
            a1d[n * 4 + (L >> 4)] = pd;
        }
    }
}

__global__ __launch_bounds__(256) void k_a2(const float* __restrict__ h2, const float* __restrict__ as_,
                                            const float* __restrict__ ad_, float* a2s, float* a2d) {
    int t = threadIdx.x;
    int w = t >> 6, lane = t & 63;
    int n = blockIdx.x * 4 + w;
    float v = h2[(size_t)n * 64 + lane];
    float ps = wsum(v * as_[lane]);
    float pd = wsum(v * ad_[lane]);
    if (lane == 0) { a2s[n] = ps; a2d[n] = pd; }
}

// ---------- GAT1 softmax: per (node, head) wave -> normalized per-edge weights ----------
__global__ __launch_bounds__(256) void k_soft1(const int* __restrict__ row_ptr, const int* __restrict__ ssrc,
                                               const float* __restrict__ a1s, const float* __restrict__ a1d,
                                               const float* __restrict__ a1es, float* __restrict__ w1) {
    int n = blockIdx.x, t = threadIdx.x;
    int h = t >> 6, L = t & 63;
    int beg = row_ptr[n], deg = row_ptr[n + 1] - beg;
    if (deg == 0) return;
    float adn = a1d[n * 4 + h];
    float m = -3.0e38f, s = 0.f;
    for (int i = L; i < deg; i += 64) {
        int pos = beg + i;
        float l = a1s[ssrc[pos] * 4 + h] + adn + a1es[(size_t)pos * 4 + h];
        l = (l > 0.f) ? l : 0.2f * l;
        if (l > m) { s = s * __expf(m - l) + 1.f; m = l; }
        else       { s += __expf(l - m); }
    }
    for (int o = 32; o; o >>= 1) {
        float mo = __shfl_xor(m, o, 64), so = __shfl_xor(s, o, 64);
        float M = fmaxf(m, mo);
        s = s * __expf(m - M) + so * __expf(mo - M);
        m = M;
    }
    float inv = 1.f / (s + 1e-16f);
    for (int i = L; i < deg; i += 64) {
        int pos = beg + i;
        float l = a1s[ssrc[pos] * 4 + h] + adn + a1es[(size_t)pos * 4 + h];
        l = (l > 0.f) ? l : 0.2f * l;
        w1[(size_t)pos * 4 + h] = __expf(l - m) * inv;
    }
}

// ---------- GAT1 gather: wave per node, lane = 4 channels ----------
__global__ __launch_bounds__(256) void k_gath1(const int* __restrict__ row_ptr, const int* __restrict__ ssrc,
                                               const float* __restrict__ w1, const u16* __restrict__ h1,
                                               const float* __restrict__ bias, u16* __restrict__ out1) {
    int t = threadIdx.x;
    int wv = t >> 6, L = t & 63;
    int n = blockIdx.x * 4 + wv;
    int beg = row_ptr[n], deg = row_ptr[n + 1] - beg;
    int hd = L >> 4;
    float a0 = 0.f, a1v = 0.f, a2v = 0.f, a3v = 0.f;
    int i = 0;
    for (; i + 2 <= deg; i += 2) {
        int p0 = beg + i, p1 = p0 + 1;
        int s0 = ssrc[p0], s1 = ssrc[p1];
        float wa = w1[(size_t)p0 * 4 + hd];
        float wb = w1[(size_t)p1 * 4 + hd];
        uint2 ua = *((const uint2*)(h1 + (size_t)s0 * 256) + L);
        uint2 ub = *((const uint2*)(h1 + (size_t)s1 * 256) + L);
        a0 += wa * lo16(ua.x) + wb * lo16(ub.x);
        a1v += wa * hi16(ua.x) + wb * hi16(ub.x);
        a2v += wa * lo16(ua.y) + wb * lo16(ub.y);
        a3v += wa * hi16(ua.y) + wb * hi16(ub.y);
    }
    if (i < deg) {
        int p0 = beg + i;
        int s0 = ssrc[p0];
        float wa = w1[(size_t)p0 * 4 + hd];
        uint2 ua = *((const uint2*)(h1 + (size_t)s0 * 256) + L);
        a0 += wa * lo16(ua.x); a1v += wa * hi16(ua.x);
        a2v += wa * lo16(ua.y); a3v += wa * hi16(ua.y);
    }
    float4 bb = *(const float4*)(bias + 4 * L);
    uint2 pk;
    pk.x = (u32)f2bf(fmaxf(a0 + bb.x, 0.f)) | ((u32)f2bf(fmaxf(a1v + bb.y, 0.f)) << 16);
    pk.y = (u32)f2bf(fmaxf(a2v + bb.z, 0.f)) | ((u32)f2bf(fmaxf(a3v + bb.w, 0.f)) << 16);
    *((uint2*)(out1 + (size_t)n * 256) + L) = pk;
}

// ---------- GAT2 softmax: wave per node ----------
__global__ __launch_bounds__(256) void k_soft2(const int* __restrict__ row_ptr, const int* __restrict__ ssrc,
                                               const float* __restrict__ a2s, const float* __restrict__ a2d,
                                               const float* __restrict__ a2es, float* __restrict__ w2) {
    int t = threadIdx.x;
    int wv = t >> 6, L = t & 63;
    int n = blockIdx.x * 4 + wv;
    int beg = row_ptr[n], deg = row_ptr[n + 1] - beg;
    if (deg == 0) return;
    float adn = a2d[n];
    float m = -3.0e38f, s = 0.f;
    for (int i = L; i < deg; i += 64) {
        int pos = beg + i;
        float l = a2s[ssrc[pos]] + adn + a2es[pos];
        l = (l > 0.f) ? l : 0.2f * l;
        if (l > m) { s = s * __expf(m - l) + 1.f; m = l; }
        else       { s += __expf(l - m); }
    }
    for (int o = 32; o; o >>= 1) {
        float mo = __shfl_xor(m, o, 64), so = __shfl_xor(s, o, 64);
        float M = fmaxf(m, mo);
        s = s * __expf(m - M) + so * __expf(mo - M);
        m = M;
    }
    float inv = 1.f / (s + 1e-16f);
    for (int i = L; i < deg; i += 64) {
        int pos = beg + i;
        float l = a2s[ssrc[pos]] + adn + a2es[pos];
        l = (l > 0.f) ? l : 0.2f * l;
        w2[pos] = __expf(l - m) * inv;
    }
}

// ---------- GAT2 gather: wave per node, lane = channel ----------
__global__ __launch_bounds__(256) void k_gath2(const int* __restrict__ row_ptr, const int* __restrict__ ssrc,
                                               const float* __restrict__ w2, const float* __restrict__ h2,
                                               const float* __restrict__ bias, float* __restrict__ hfin) {
    int t = threadIdx.x;
    int wv = t >> 6, L = t & 63;
    int n = blockIdx.x * 4 + wv;
    int beg = row_ptr[n], deg = row_ptr[n + 1] - beg;
    float acc = 0.f;
    int i = 0;
    for (; i + 2 <= deg; i += 2) {
        int p0 = beg + i, p1 = p0 + 1;
        int s0 = ssrc[p0], s1 = ssrc[p1];
        float wa = w2[p0], wb = w2[p1];
        float va = h2[(size_t)s0 * 64 + L];
        float vb = h2[(size_t)s1 * 64 + L];
        acc += wa * va + wb * vb;
    }
    if (i < deg) {
        int p0 = beg + i;
        acc += w2[p0] * h2[(size_t)ssrc[p0] * 64 + L];
    }
    hfin[(size_t)n * 64 + L] = acc + bias[L];
}

// ---------- global-attention pooling + classifier: block (1 wave) per graph ----------
__global__ __launch_bounds__(64) void k_pool(const int* __restrict__ bvec, const float* __restrict__ hf,
                                             const float* gateW, const float* gateb,
                                             const float* __restrict__ scene,
                                             const float* c1W, const float* c1b,
                                             const float* c2W, const float* c2b,
                                             float* __restrict__ outp) {
    int b = blockIdx.x, lane = threadIdx.x;
    __shared__ float gwl[64], se[64], comb[192], hid[64];
    gwl[lane] = gateW[lane];
    __syncthreads();
    int s0, s1;
    { int lo = 0, hi = N_NODES; while (lo < hi) { int mid = (lo + hi) >> 1; if (bvec[mid] < b) lo = mid + 1; else hi = mid; } s0 = lo; }
    { int lo = 0, hi = N_NODES; while (lo < hi) { int mid = (lo + hi) >> 1; if (bvec[mid] < b + 1) lo = mid + 1; else hi = mid; } s1 = lo; }
    float gb = gateb[0];
    float m = -3.0e38f, ssum = 0.f, acc = 0.f;
    for (int cs = s0; cs < s1; cs += 64) {
        int cnt = min(64, s1 - cs);
        float l = -3.0e38f;
        if (lane < cnt) {
            int n = cs + lane;
            float d = 0.f;
            for (int i = 0; i < 64; i++) d += hf[(size_t)n * 64 + i] * gwl[i];
            l = d + gb;
        }
        float cm = wmax(l);
        float newm = fmaxf(m, cm);
        float rsc = __expf(m - newm);
        float e = (lane < cnt) ? __expf(l - newm) : 0.f;
        float es = wsum(e);
        ssum = ssum * rsc + es;
        se[lane] = e;
        __syncthreads();
        float a2 = 0.f;
        for (int i = 0; i < cnt; i++) a2 += se[i] * hf[(size_t)(cs + i) * 64 + lane];
        acc = acc * rsc + a2;
        __syncthreads();
        m = newm;
    }
    float rel = acc / (ssum + 1e-16f);
    comb[lane] = scene[b * 128 + lane];
    comb[64 + lane] = scene[b * 128 + 64 + lane];
    comb[128 + lane] = rel;
    __syncthreads();
    float hj = 0.f;
    for (int k = 0; k < 192; k++) hj += comb[k] * c1W[k * 64 + lane];
    hj += c1b[lane];
    hid[lane] = fmaxf(hj, 0.f);
    __syncthreads();
    if (lane < 3) {
        float o = 0.f;
        for (int k = 0; k < 64; k++) o += hid[k] * c2W[k * 3 + lane];
        o += c2b[lane];
        outp[b * 3 + lane] = o;
    }
}

extern "C" void kernel_launch(void* const* d_in, const int* in_sizes, int n_in,
                              void* d_out, int out_size, void* d_ws, size_t ws_size,
                              hipStream_t stream) {
    (void)in_sizes; (void)n_in; (void)out_size; (void)ws_size;
    const float* gf     = (const float*)d_in[0];
    const float* x      = (const float*)d_in[1];
    const float* roi    = (const float*)d_in[2];
    const int*   ei     = (const int*)d_in[3];
    const float* ea     = (const float*)d_in[4];
    const int*   bvec   = (const int*)d_in[5];
    const float* roiW   = (const float*)d_in[6];
    const float* roib   = (const float*)d_in[7];
    const float* sceneW = (const float*)d_in[8];
    const float* sceneb = (const float*)d_in[9];
    const float* g1W    = (const float*)d_in[10];
    const float* g1as   = (const float*)d_in[11];
    const float* g1ad   = (const float*)d_in[12];
    const float* g1We   = (const float*)d_in[13];
    const float* g1ae   = (const float*)d_in[14];
    const float* g1b    = (const float*)d_in[15];
    const float* g2W    = (const float*)d_in[16];
    const float* g2as   = (const float*)d_in[17];
    const float* g2ad   = (const float*)d_in[18];
    const float* g2We   = (const float*)d_in[19];
    const float* g2ae   = (const float*)d_in[20];
    const float* g2b    = (const float*)d_in[21];
    const float* gateW  = (const float*)d_in[22];
    const float* gateb  = (const float*)d_in[23];
    const float* c1W    = (const float*)d_in[24];
    const float* c1b    = (const float*)d_in[25];
    const float* c2W    = (const float*)d_in[26];
    const float* c2b    = (const float*)d_in[27];

    char* w = (char*)d_ws;
    size_t o = 0;
    auto nxt = [&](size_t bytes) -> char* {
        char* p = w + o;
        o += (bytes + 255) & ~(size_t)255;
        return p;
    };
    float* scene  = (float*)nxt((size_t)NB * 128 * 4);
    float* M1     = (float*)nxt(80);
    float* M2     = (float*)nxt(32);
    int* cnt      = (int*)nxt((size_t)N_NODES * 4);
    int* pre      = (int*)nxt((size_t)N_NODES * 4);
    int* bsum     = (int*)nxt(64 * 4);
    int* row_ptr  = (int*)nxt((size_t)(N_NODES + 1) * 4);
    int* cursor   = (int*)nxt((size_t)N_NODES * 4);
    int* ssrc     = (int*)nxt((size_t)N_EDGES * 4);
    float* a1es   = (float*)nxt((size_t)N_EDGES * 16);
    float* a2es   = (float*)nxt((size_t)N_EDGES * 4);
    float* visbuf = (float*)nxt((size_t)N_NODES * 64 * 4);   // vis, later aliased as w2
    u16* h1       = (u16*)nxt((size_t)N_NODES * 256 * 2);
    u16* out1     = (u16*)nxt((size_t)N_NODES * 256 * 2);
    float* w1buf  = (float*)nxt((size_t)N_EDGES * 16);       // w1, later aliased as h2
    float* hfin   = (float*)nxt((size_t)N_NODES * 64 * 4);
    float* a1s    = (float*)nxt((size_t)N_NODES * 16);
    float* a1d    = (float*)nxt((size_t)N_NODES * 16);
    float* a2s    = (float*)nxt((size_t)N_NODES * 4);
    float* a2d    = (float*)nxt((size_t)N_NODES * 4);

    float* vis = visbuf;
    float* w2  = visbuf;      // vis dead after k_h1; w2 written by k_soft2 (later)
    float* w1  = w1buf;
    float* h2  = w1buf;       // w1 dead after k_gath1; h2 written by k_h2 (later)

    hipMemsetAsync(cnt, 0, (size_t)N_NODES * 4, stream);
    k_prep<<<1, 32, 0, stream>>>(g1We, g1ae, g2We, g2ae, M1, M2);
    k_scene<<<(NB * 128) / 256, 256, 0, stream>>>(gf, sceneW, sceneb, scene);
    k_hist<<<N_EDGES / 256, 256, 0, stream>>>(ei, cnt);
    k_scan_blk<<<64, 256, 0, stream>>>(cnt, pre, bsum);
    k_scan_top<<<1, 64, 0, stream>>>(bsum);
    k_scan_fix<<<N_NODES / 256, 256, 0, stream>>>(pre, bsum, row_ptr, cursor);
    k_scatter<<<N_EDGES / 256, 256, 0, stream>>>(ei, ea, M1, M2, cursor, ssrc, a1es, a2es);
    k_vis<<<N_NODES / 64, 256, 0, stream>>>(roi, roiW, roib, vis);
    k_h1<<<dim3(N_NODES / 32, 2), 256, 0, stream>>>(x, vis, g1W, h1);
    k_a1<<<N_NODES / 64, 256, 0, stream>>>(h1, g1as, g1ad, a1s, a1d);
    k_soft1<<<N_NODES, 256, 0, stream>>>(row_ptr, ssrc, a1s, a1d, a1es, w1);
    k_gath1<<<N_NODES / 4, 256, 0, stream>>>(row_ptr, ssrc, w1, h1, g1b, out1);
    k_h2<<<N_NODES / 64, 256, 0, stream>>>(out1, g2W, h2);
    k_a2<<<N_NODES / 4, 256, 0, stream>>>(h2, g2as, g2ad, a2s, a2d);
    k_soft2<<<N_NODES / 4, 256, 0, stream>>>(row_ptr, ssrc, a2s, a2d, a2es, w2);
    k_gath2<<<N_NODES / 4, 256, 0, stream>>>(row_ptr, ssrc, w2, h2, g2b, hfin);
    k_pool<<<NB, 64, 0, stream>>>(bvec, hfin, gateW, gateb, scene, c1W, c1b, c2W, c2b, (float*)d_out);
}

// Round 5
// 712.156 us; speedup vs baseline: 1.7126x; 1.0461x over previous
//
#include <hip/hip_runtime.h>

#define N_NODES 65536
#define N_EDGES 1048576
#define NB      512

typedef unsigned short u16;
typedef unsigned int   u32;
typedef unsigned long long u64;

__device__ __forceinline__ float bf2f(u16 u) { return __uint_as_float(((u32)u) << 16); }
__device__ __forceinline__ float lo16(u32 u) { return __uint_as_float(u << 16); }
__device__ __forceinline__ float hi16(u32 u) { return __uint_as_float(u & 0xffff0000u); }
__device__ __forceinline__ u16 f2bf(float f) {
    u32 u = __float_as_uint(f);
    u32 r = (u + 0x7fffu + ((u >> 16) & 1u)) >> 16;
    return (u16)r;
}
__device__ __forceinline__ float wsum(float v) {
    for (int o = 32; o; o >>= 1) v += __shfl_xor(v, o, 64);
    return v;
}
__device__ __forceinline__ float wmax(float v) {
    for (int o = 32; o; o >>= 1) v = fmaxf(v, __shfl_xor(v, o, 64));
    return v;
}

// ---------- tiny precompute: M1[j*4+h] = sum_c We1[j,h*64+c]*ae1[h,c]; M2[j] likewise ----------
__global__ void k_prep(const float* g1We, const float* g1ae, const float* g2We, const float* g2ae,
                       float* M1, float* M2) {
    int t = threadIdx.x;
    if (t < 20) {
        int j = t >> 2, h = t & 3;
        float s = 0.f;
        for (int c = 0; c < 64; c++) s += g1We[j * 256 + h * 64 + c] * g1ae[h * 64 + c];
        M1[t] = s;
    } else if (t < 25) {
        int j = t - 20;
        float s = 0.f;
        for (int c = 0; c < 64; c++) s += g2We[j * 64 + c] * g2ae[c];
        M2[j] = s;
    }
}

// ---------- scene = global_feat @ scene_W + b  (512x512x128) ----------
__global__ __launch_bounds__(256) void k_scene(const float* __restrict__ gf, const float* __restrict__ W,
                                               const float* __restrict__ bias, float* __restrict__ scene) {
    int idx = blockIdx.x * 256 + threadIdx.x;
    int b = idx >> 7, j = idx & 127;
    float acc = 0.f;
    for (int k = 0; k < 512; k++) acc += gf[b * 512 + k] * W[k * 128 + j];
    scene[idx] = acc + bias[j];
}

// ---------- counting sort of edges by dst ----------
__global__ __launch_bounds__(256) void k_hist(const int* ei, int* cnt) {
    int e = blockIdx.x * 256 + threadIdx.x;
    atomicAdd(&cnt[ei[N_EDGES + e]], 1);
}

// ---------- hierarchical exclusive scan of cnt[65536] ----------
__global__ __launch_bounds__(256) void k_scan_blk(const int* __restrict__ cnt, int* __restrict__ pre,
                                                  int* __restrict__ bsum) {
    __shared__ int sd[256];
    int t = threadIdx.x, b = blockIdx.x;
    int base = b * 1024 + t * 4;
    int4 c = *(const int4*)(cnt + base);
    int s = c.x + c.y + c.z + c.w;
    sd[t] = s;
    __syncthreads();
    for (int off = 1; off < 256; off <<= 1) {
        int v = (t >= off) ? sd[t - off] : 0;
        __syncthreads();
        sd[t] += v;
        __syncthreads();
    }
    int excl = sd[t] - s;
    int4 p;
    p.x = excl;
    p.y = excl + c.x;
    p.z = excl + c.x + c.y;
    p.w = excl + c.x + c.y + c.z;
    *(int4*)(pre + base) = p;
    if (t == 255) bsum[b] = sd[255];
}

__global__ __launch_bounds__(64) void k_scan_top(int* bsum) {
    int t = threadIdx.x;
    int v = bsum[t];
    int inc = v;
    for (int off = 1; off < 64; off <<= 1) {
        int u = __shfl_up(inc, off, 64);
        if (t >= off) inc += u;
    }
    bsum[t] = inc - v;
}

__global__ __launch_bounds__(256) void k_scan_fix(const int* __restrict__ pre, const int* __restrict__ bsum,
                                                  int* __restrict__ row_ptr, int* __restrict__ cursor) {
    int i = blockIdx.x * 256 + threadIdx.x;
    int v = pre[i] + bsum[i >> 10];
    row_ptr[i] = v;
    cursor[i] = v;
    if (i == 0) row_ptr[N_NODES] = N_EDGES;
}

// ---------- minimal scatter: one 8B packed word per edge ----------
__global__ __launch_bounds__(256) void k_scatter(const int* __restrict__ ei, int* cursor,
                                                 u64* __restrict__ epack) {
    int e = blockIdx.x * 256 + threadIdx.x;
    int src = ei[e];
    int d = ei[N_EDGES + e];
    int pos = atomicAdd(&cursor[d], 1);
    epack[pos] = ((u64)(u32)e << 32) | (u32)src;
}

// ---------- payload pass in pos order: coalesced writes, random 20B reads of ea ----------
__global__ __launch_bounds__(256) void k_payload(const u64* __restrict__ epack, const float* __restrict__ ea,
                                                 const float* __restrict__ M1, const float* __restrict__ M2,
                                                 int* __restrict__ ssrc, float* __restrict__ a1es,
                                                 float* __restrict__ a2es) {
    int pos = blockIdx.x * 256 + threadIdx.x;
    u64 p = epack[pos];
    int src = (int)(u32)p;
    int e = (int)(p >> 32);
    ssrc[pos] = src;
    float v[5];
    for (int j = 0; j < 5; j++) v[j] = ea[(size_t)e * 5 + j];
    float4 o;
    o.x = v[0]*M1[0]  + v[1]*M1[4]  + v[2]*M1[8]  + v[3]*M1[12] + v[4]*M1[16];
    o.y = v[0]*M1[1]  + v[1]*M1[5]  + v[2]*M1[9]  + v[3]*M1[13] + v[4]*M1[17];
    o.z = v[0]*M1[2]  + v[1]*M1[6]  + v[2]*M1[10] + v[3]*M1[14] + v[4]*M1[18];
    o.w = v[0]*M1[3]  + v[1]*M1[7]  + v[2]*M1[11] + v[3]*M1[15] + v[4]*M1[19];
    *(float4*)(a1es + (size_t)pos * 4) = o;
    a2es[pos] = v[0]*M2[0] + v[1]*M2[1] + v[2]*M2[2] + v[3]*M2[3] + v[4]*M2[4];
}

// ---------- register-blocked GEMM: vis = relu(roi @ roiW + b)  (Nx256)@(256x64) fp32 ----------
__global__ __launch_bounds__(256) void k_vis(const float* __restrict__ A, const float* __restrict__ W,
                                             const float* __restrict__ bias, float* __restrict__ out) {
    __shared__ float At[64][68];
    __shared__ float Wl[64][68];
    int t = threadIdx.x;
    int n0 = blockIdx.x * 64;
    int cg = t & 15, rg = t >> 4;
    int sr = t >> 2, scs = (t & 3) * 16;
    float acc[4][4];
    for (int i = 0; i < 4; i++) for (int j = 0; j < 4; j++) acc[i][j] = 0.f;
    for (int kc = 0; kc < 4; kc++) {
        __syncthreads();
        const float* ap = A + (size_t)(n0 + sr) * 256 + kc * 64 + scs;
        float4 q0 = *(const float4*)ap, q1 = *(const float4*)(ap + 4);
        float4 q2 = *(const float4*)(ap + 8), q3 = *(const float4*)(ap + 12);
        At[scs + 0][sr] = q0.x;  At[scs + 1][sr] = q0.y;  At[scs + 2][sr] = q0.z;  At[scs + 3][sr] = q0.w;
        At[scs + 4][sr] = q1.x;  At[scs + 5][sr] = q1.y;  At[scs + 6][sr] = q1.z;  At[scs + 7][sr] = q1.w;
        At[scs + 8][sr] = q2.x;  At[scs + 9][sr] = q2.y;  At[scs + 10][sr] = q2.z; At[scs + 11][sr] = q2.w;
        At[scs + 12][sr] = q3.x; At[scs + 13][sr] = q3.y; At[scs + 14][sr] = q3.z; At[scs + 15][sr] = q3.w;
        const float* wp = W + (size_t)(kc * 64 + sr) * 64 + scs;
        *(float4*)&Wl[sr][scs + 0]  = *(const float4*)wp;
        *(float4*)&Wl[sr][scs + 4]  = *(const float4*)(wp + 4);
        *(float4*)&Wl[sr][scs + 8]  = *(const float4*)(wp + 8);
        *(float4*)&Wl[sr][scs + 12] = *(const float4*)(wp + 12);
        __syncthreads();
        for (int k = 0; k < 64; k++) {
            float4 a4 = *(const float4*)&At[k][rg * 4];
            float4 w4 = *(const float4*)&Wl[k][cg * 4];
            acc[0][0] += a4.x * w4.x; acc[0][1] += a4.x * w4.y; acc[0][2] += a4.x * w4.z; acc[0][3] += a4.x * w4.w;
            acc[1][0] += a4.y * w4.x; acc[1][1] += a4.y * w4.y; acc[1][2] += a4.y * w4.z; acc[1][3] += a4.y * w4.w;
            acc[2][0] += a4.z * w4.x; acc[2][1] += a4.z * w4.y; acc[2][2] += a4.z * w4.z; acc[2][3] += a4.z * w4.w;
            acc[3][0] += a4.w * w4.x; acc[3][1] += a4.w * w4.y; acc[3][2] += a4.w * w4.z; acc[3][3] += a4.w * w4.w;
        }
    }
    float4 bb = *(const float4*)(bias + cg * 4);
    for (int i = 0; i < 4; i++) {
        float4 o;
        o.x = fmaxf(acc[i][0] + bb.x, 0.f);
        o.y = fmaxf(acc[i][1] + bb.y, 0.f);
        o.z = fmaxf(acc[i][2] + bb.z, 0.f);
        o.w = fmaxf(acc[i][3] + bb.w, 0.f);
        *(float4*)(out + (size_t)(n0 + rg * 4 + i) * 64 + cg * 4) = o;
    }
}

// ---------- register-blocked GEMM: h2 = out1(bf16) @ g2W  (Nx256)@(256x64) -> fp32 ----------
__global__ __launch_bounds__(256) void k_h2(const u16* __restrict__ A, const float* __restrict__ W,
                                            float* __restrict__ out) {
    __shared__ float At[64][68];
    __shared__ float Wl[64][68];
    int t = threadIdx.x;
    int n0 = blockIdx.x * 64;
    int cg = t & 15, rg = t >> 4;
    int sr = t >> 2, scs = (t & 3) * 16;
    float acc[4][4];
    for (int i = 0; i < 4; i++) for (int j = 0; j < 4; j++) acc[i][j] = 0.f;
    for (int kc = 0; kc < 4; kc++) {
        __syncthreads();
        const u16* ap = A + (size_t)(n0 + sr) * 256 + kc * 64 + scs;
        uint4 u0 = *(const uint4*)ap;
        uint4 u1 = *(const uint4*)(ap + 8);
        At[scs + 0][sr] = lo16(u0.x);  At[scs + 1][sr] = hi16(u0.x);
        At[scs + 2][sr] = lo16(u0.y);  At[scs + 3][sr] = hi16(u0.y);
        At[scs + 4][sr] = lo16(u0.z);  At[scs + 5][sr] = hi16(u0.z);
        At[scs + 6][sr] = lo16(u0.w);  At[scs + 7][sr] = hi16(u0.w);
        At[scs + 8][sr] = lo16(u1.x);  At[scs + 9][sr] = hi16(u1.x);
        At[scs + 10][sr] = lo16(u1.y); At[scs + 11][sr] = hi16(u1.y);
        At[scs + 12][sr] = lo16(u1.z); At[scs + 13][sr] = hi16(u1.z);
        At[scs + 14][sr] = lo16(u1.w); At[scs + 15][sr] = hi16(u1.w);
        const float* wp = W + (size_t)(kc * 64 + sr) * 64 + scs;
        *(float4*)&Wl[sr][scs + 0]  = *(const float4*)wp;
        *(float4*)&Wl[sr][scs + 4]  = *(const float4*)(wp + 4);
        *(float4*)&Wl[sr][scs + 8]  = *(const float4*)(wp + 8);
        *(float4*)&Wl[sr][scs + 12] = *(const float4*)(wp + 12);
        __syncthreads();
        for (int k = 0; k < 64; k++) {
            float4 a4 = *(const float4*)&At[k][rg * 4];
            float4 w4 = *(const float4*)&Wl[k][cg * 4];
            acc[0][0] += a4.x * w4.x; acc[0][1] += a4.x * w4.y; acc[0][2] += a4.x * w4.z; acc[0][3] += a4.x * w4.w;
            acc[1][0] += a4.y * w4.x; acc[1][1] += a4.y * w4.y; acc[1][2] += a4.y * w4.z; acc[1][3] += a4.y * w4.w;
            acc[2][0] += a4.z * w4.x; acc[2][1] += a4.z * w4.y; acc[2][2] += a4.z * w4.z; acc[2][3] += a4.z * w4.w;
            acc[3][0] += a4.w * w4.x; acc[3][1] += a4.w * w4.y; acc[3][2] += a4.w * w4.z; acc[3][3] += a4.w * w4.w;
        }
    }
    for (int i = 0; i < 4; i++) {
        float4 o = make_float4(acc[i][0], acc[i][1], acc[i][2], acc[i][3]);
        *(float4*)(out + (size_t)(n0 + rg * 4 + i) * 64 + cg * 4) = o;
    }
}

// ---------- h1 = [x | vis] @ g1_W  (Nx77)@(77x256) -> bf16; col-half via blockIdx.y ----------
__global__ __launch_bounds__(256) void k_h1(const float* __restrict__ x, const float* __restrict__ vis,
                                            const float* __restrict__ g1W, u16* __restrict__ h1) {
    __shared__ float At[77][36];
    __shared__ float Wl[77][132];
    int t = threadIdx.x, ch = blockIdx.y;
    int n0 = blockIdx.x * 32;
    int cg = t & 31, rg = t >> 5;
    for (int idx = t; idx < 9856; idx += 256) {
        int k = idx >> 7, c = idx & 127;
        Wl[k][c] = g1W[(size_t)k * 256 + ch * 128 + c];
    }
    for (int idx = t; idx < 2464; idx += 256) {
        int r = idx / 77, k = idx - r * 77;
        At[k][r] = (k < 13) ? x[(size_t)(n0 + r) * 13 + k] : vis[(size_t)(n0 + r) * 64 + (k - 13)];
    }
    __syncthreads();
    float acc[4][4];
    for (int i = 0; i < 4; i++) for (int j = 0; j < 4; j++) acc[i][j] = 0.f;
    for (int k = 0; k < 77; k++) {
        float4 a4 = *(const float4*)&At[k][rg * 4];
        float4 w4 = *(const float4*)&Wl[k][cg * 4];
        acc[0][0] += a4.x * w4.x; acc[0][1] += a4.x * w4.y; acc[0][2] += a4.x * w4.z; acc[0][3] += a4.x * w4.w;
        acc[1][0] += a4.y * w4.x; acc[1][1] += a4.y * w4.y; acc[1][2] += a4.y * w4.z; acc[1][3] += a4.y * w4.w;
        acc[2][0] += a4.z * w4.x; acc[2][1] += a4.z * w4.y; acc[2][2] += a4.z * w4.z; acc[2][3] += a4.z * w4.w;
        acc[3][0] += a4.w * w4.x; acc[3][1] += a4.w * w4.y; acc[3][2] += a4.w * w4.z; acc[3][3] += a4.w * w4.w;
    }
    for (int i = 0; i < 4; i++) {
        uint2 pk;
        pk.x = (u32)f2bf(acc[i][0]) | ((u32)f2bf(acc[i][1]) << 16);
        pk.y = (u32)f2bf(acc[i][2]) | ((u32)f2bf(acc[i][3]) << 16);
        *(uint2*)(h1 + (size_t)(n0 + rg * 4 + i) * 256 + ch * 128 + cg * 4) = pk;
    }
}

// ---------- a1_s/a1_d: vectorized, wave handles 16 nodes ----------
__global__ __launch_bounds__(256) void k_a1(const u16* __restrict__ h1, const float* __restrict__ as_,
                                            const float* __restrict__ ad_, float* a1s, float* a1d) {
    int t = threadIdx.x;
    int w = t >> 6, L = t & 63;
    float4 as4 = *(const float4*)(as_ + 4 * L);
    float4 ad4 = *(const float4*)(ad_ + 4 * L);
    int base = (blockIdx.x * 4 + w) * 16;
    for (int j = 0; j < 16; j++) {
        int n = base + j;
        uint2 u = *((const uint2*)(h1 + (size_t)n * 256) + L);
        float v0 = lo16(u.x), v1 = hi16(u.x), v2 = lo16(u.y), v3 = hi16(u.y);
        float ps = v0 * as4.x + v1 * as4.y + v2 * as4.z + v3 * as4.w;
        float pd = v0 * ad4.x + v1 * ad4.y + v2 * ad4.z + v3 * ad4.w;
        for (int o = 1; o < 16; o <<= 1) { ps += __shfl_xor(ps, o, 64); pd += __shfl_xor(pd, o, 64); }
        if ((L & 15) == 0) {
            a1s[n * 4 + (L >> 4)] = ps;
            a1d[n * 4 + (L >> 4)] = pd;
        }
    }
}

__global__ __launch_bounds__(256) void k_a2(const float* __restrict__ h2, const float* __restrict__ as_,
                                            const float* __restrict__ ad_, float* a2s, float* a2d) {
    int t = threadIdx.x;
    int w = t >> 6, lane = t & 63;
    int n = blockIdx.x * 4 + w;
    float v = h2[(size_t)n * 64 + lane];
    float ps = wsum(v * as_[lane]);
    float pd = wsum(v * ad_[lane]);
    if (lane == 0) { a2s[n] = ps; a2d[n] = pd; }
}

// ---------- GAT1 softmax: wave per node, 16-lane group per head ----------
__global__ __launch_bounds__(256) void k_soft1(const int* __restrict__ row_ptr, const int* __restrict__ ssrc,
                                               const float* __restrict__ a1s, const float* __restrict__ a1d,
                                               const float* __restrict__ a1es, float* __restrict__ w1) {
    int t = threadIdx.x;
    int wv = t >> 6, L = t & 63;
    int n = blockIdx.x * 4 + wv;
    int h = L >> 4, j = L & 15;
    int beg = row_ptr[n], deg = row_ptr[n + 1] - beg;
    if (deg == 0) return;
    float adn = a1d[n * 4 + h];
    float m = -3.0e38f, s = 0.f;
    for (int i = j; i < deg; i += 16) {
        int pos = beg + i;
        float l = a1s[ssrc[pos] * 4 + h] + adn + a1es[(size_t)pos * 4 + h];
        l = (l > 0.f) ? l : 0.2f * l;
        if (l > m) { s = s * __expf(m - l) + 1.f; m = l; }
        else       { s += __expf(l - m); }
    }
    for (int o = 1; o < 16; o <<= 1) {
        float mo = __shfl_xor(m, o, 64), so = __shfl_xor(s, o, 64);
        float M = fmaxf(m, mo);
        s = s * __expf(m - M) + so * __expf(mo - M);
        m = M;
    }
    float inv = 1.f / (s + 1e-16f);
    for (int i = j; i < deg; i += 16) {
        int pos = beg + i;
        float l = a1s[ssrc[pos] * 4 + h] + adn + a1es[(size_t)pos * 4 + h];
        l = (l > 0.f) ? l : 0.2f * l;
        w1[(size_t)pos * 4 + h] = __expf(l - m) * inv;
    }
}

// ---------- GAT1 gather: wave per node, lane = 4 channels ----------
__global__ __launch_bounds__(256) void k_gath1(const int* __restrict__ row_ptr, const int* __restrict__ ssrc,
                                               const float* __restrict__ w1, const u16* __restrict__ h1,
                                               const float* __restrict__ bias, u16* __restrict__ out1) {
    int t = threadIdx.x;
    int wv = t >> 6, L = t & 63;
    int n = blockIdx.x * 4 + wv;
    int beg = row_ptr[n], deg = row_ptr[n + 1] - beg;
    int hd = L >> 4;
    float a0 = 0.f, a1v = 0.f, a2v = 0.f, a3v = 0.f;
    int i = 0;
    for (; i + 2 <= deg; i += 2) {
        int p0 = beg + i, p1 = p0 + 1;
        int s0 = ssrc[p0], s1 = ssrc[p1];
        float wa = w1[(size_t)p0 * 4 + hd];
        float wb = w1[(size_t)p1 * 4 + hd];
        uint2 ua = *((const uint2*)(h1 + (size_t)s0 * 256) + L);
        uint2 ub = *((const uint2*)(h1 + (size_t)s1 * 256) + L);
        a0 += wa * lo16(ua.x) + wb * lo16(ub.x);
        a1v += wa * hi16(ua.x) + wb * hi16(ub.x);
        a2v += wa * lo16(ua.y) + wb * lo16(ub.y);
        a3v += wa * hi16(ua.y) + wb * hi16(ub.y);
    }
    if (i < deg) {
        int p0 = beg + i;
        int s0 = ssrc[p0];
        float wa = w1[(size_t)p0 * 4 + hd];
        uint2 ua = *((const uint2*)(h1 + (size_t)s0 * 256) + L);
        a0 += wa * lo16(ua.x); a1v += wa * hi16(ua.x);
        a2v += wa * lo16(ua.y); a3v += wa * hi16(ua.y);
    }
    float4 bb = *(const float4*)(bias + 4 * L);
    uint2 pk;
    pk.x = (u32)f2bf(fmaxf(a0 + bb.x, 0.f)) | ((u32)f2bf(fmaxf(a1v + bb.y, 0.f)) << 16);
    pk.y = (u32)f2bf(fmaxf(a2v + bb.z, 0.f)) | ((u32)f2bf(fmaxf(a3v + bb.w, 0.f)) << 16);
    *((uint2*)(out1 + (size_t)n * 256) + L) = pk;
}

// ---------- GAT2 softmax: wave per 4 nodes, 16-lane group per node ----------
__global__ __launch_bounds__(256) void k_soft2(const int* __restrict__ row_ptr, const int* __restrict__ ssrc,
                                               const float* __restrict__ a2s, const float* __restrict__ a2d,
                                               const float* __restrict__ a2es, float* __restrict__ w2) {
    int t = threadIdx.x;
    int wv = t >> 6, L = t & 63;
    int g = L >> 4, j = L & 15;
    int n = blockIdx.x * 16 + wv * 4 + g;
    int beg = row_ptr[n], deg = row_ptr[n + 1] - beg;
    if (deg == 0) return;
    float adn = a2d[n];
    float m = -3.0e38f, s = 0.f;
    for (int i = j; i < deg; i += 16) {
        int pos = beg + i;
        float l = a2s[ssrc[pos]] + adn + a2es[pos];
        l = (l > 0.f) ? l : 0.2f * l;
        if (l > m) { s = s * __expf(m - l) + 1.f; m = l; }
        else       { s += __expf(l - m); }
    }
    for (int o = 1; o < 16; o <<= 1) {
        float mo = __shfl_xor(m, o, 64), so = __shfl_xor(s, o, 64);
        float M = fmaxf(m, mo);
        s = s * __expf(m - M) + so * __expf(mo - M);
        m = M;
    }
    float inv = 1.f / (s + 1e-16f);
    for (int i = j; i < deg; i += 16) {
        int pos = beg + i;
        float l = a2s[ssrc[pos]] + adn + a2es[pos];
        l = (l > 0.f) ? l : 0.2f * l;
        w2[pos] = __expf(l - m) * inv;
    }
}

// ---------- GAT2 gather: wave per node, lane = channel ----------
__global__ __launch_bounds__(256) void k_gath2(const int* __restrict__ row_ptr, const int* __restrict__ ssrc,
                                               const float* __restrict__ w2, const float* __restrict__ h2,
                                               const float* __restrict__ bias, float* __restrict__ hfin) {
    int t = threadIdx.x;
    int wv = t >> 6, L = t & 63;
    int n = blockIdx.x * 4 + wv;
    int beg = row_ptr[n], deg = row_ptr[n + 1] - beg;
    float acc = 0.f;
    int i = 0;
    for (; i + 2 <= deg; i += 2) {
        int p0 = beg + i, p1 = p0 + 1;
        int s0 = ssrc[p0], s1 = ssrc[p1];
        float wa = w2[p0], wb = w2[p1];
        float va = h2[(size_t)s0 * 64 + L];
        float vb = h2[(size_t)s1 * 64 + L];
        acc += wa * va + wb * vb;
    }
    if (i < deg) {
        int p0 = beg + i;
        acc += w2[p0] * h2[(size_t)ssrc[p0] * 64 + L];
    }
    hfin[(size_t)n * 64 + L] = acc + bias[L];
}

// ---------- global-attention pooling + classifier: block (1 wave) per graph ----------
__global__ __launch_bounds__(64) void k_pool(const int* __restrict__ bvec, const float* __restrict__ hf,
                                             const float* gateW, const float* gateb,
                                             const float* __restrict__ scene,
                                             const float* c1W, const float* c1b,
                                             const float* c2W, const float* c2b,
                                             float* __restrict__ outp) {
    int b = blockIdx.x, lane = threadIdx.x;
    __shared__ float gwl[64], se[64], comb[192], hid[64];
    gwl[lane] = gateW[lane];
    __syncthreads();
    int s0, s1;
    { int lo = 0, hi = N_NODES; while (lo < hi) { int mid = (lo + hi) >> 1; if (bvec[mid] < b) lo = mid + 1; else hi = mid; } s0 = lo; }
    { int lo = 0, hi = N_NODES; while (lo < hi) { int mid = (lo + hi) >> 1; if (bvec[mid] < b + 1) lo = mid + 1; else hi = mid; } s1 = lo; }
    float gb = gateb[0];
    float m = -3.0e38f, ssum = 0.f, acc = 0.f;
    for (int cs = s0; cs < s1; cs += 64) {
        int cnt = min(64, s1 - cs);
        float l = -3.0e38f;
        if (lane < cnt) {
            int n = cs + lane;
            float d = 0.f;
            for (int i = 0; i < 64; i++) d += hf[(size_t)n * 64 + i] * gwl[i];
            l = d + gb;
        }
        float cm = wmax(l);
        float newm = fmaxf(m, cm);
        float rsc = __expf(m - newm);
        float e = (lane < cnt) ? __expf(l - newm) : 0.f;
        float es = wsum(e);
        ssum = ssum * rsc + es;
        se[lane] = e;
        __syncthreads();
        float a2 = 0.f;
        for (int i = 0; i < cnt; i++) a2 += se[i] * hf[(size_t)(cs + i) * 64 + lane];
        acc = acc * rsc + a2;
        __syncthreads();
        m = newm;
    }
    float rel = acc / (ssum + 1e-16f);
    comb[lane] = scene[b * 128 + lane];
    comb[64 + lane] = scene[b * 128 + 64 + lane];
    comb[128 + lane] = rel;
    __syncthreads();
    float hj = 0.f;
    for (int k = 0; k < 192; k++) hj += comb[k] * c1W[k * 64 + lane];
    hj += c1b[lane];
    hid[lane] = fmaxf(hj, 0.f);
    __syncthreads();
    if (lane < 3) {
        float o = 0.f;
        for (int k = 0; k < 64; k++) o += hid[k] * c2W[k * 3 + lane];
        o += c2b[lane];
        outp[b * 3 + lane] = o;
    }
}

extern "C" void kernel_launch(void* const* d_in, const int* in_sizes, int n_in,
                              void* d_out, int out_size, void* d_ws, size_t ws_size,
                              hipStream_t stream) {
    (void)in_sizes; (void)n_in; (void)out_size; (void)ws_size;
    const float* gf     = (const float*)d_in[0];
    const float* x      = (const float*)d_in[1];
    const float* roi    = (const float*)d_in[2];
    const int*   ei     = (const int*)d_in[3];
    const float* ea     = (const float*)d_in[4];
    const int*   bvec   = (const int*)d_in[5];
    const float* roiW   = (const float*)d_in[6];
    const float* roib   = (const float*)d_in[7];
    const float* sceneW = (const float*)d_in[8];
    const float* sceneb = (const float*)d_in[9];
    const float* g1W    = (const float*)d_in[10];
    const float* g1as   = (const float*)d_in[11];
    const float* g1ad   = (const float*)d_in[12];
    const float* g1We   = (const float*)d_in[13];
    const float* g1ae   = (const float*)d_in[14];
    const float* g1b    = (const float*)d_in[15];
    const float* g2W    = (const float*)d_in[16];
    const float* g2as   = (const float*)d_in[17];
    const float* g2ad   = (const float*)d_in[18];
    const float* g2We   = (const float*)d_in[19];
    const float* g2ae   = (const float*)d_in[20];
    const float* g2b    = (const float*)d_in[21];
    const float* gateW  = (const float*)d_in[22];
    const float* gateb  = (const float*)d_in[23];
    const float* c1W    = (const float*)d_in[24];
    const float* c1b    = (const float*)d_in[25];
    const float* c2W    = (const float*)d_in[26];
    const float* c2b    = (const float*)d_in[27];

    char* w = (char*)d_ws;
    size_t o = 0;
    auto nxt = [&](size_t bytes) -> char* {
        char* p = w + o;
        o += (bytes + 255) & ~(size_t)255;
        return p;
    };
    float* scene  = (float*)nxt((size_t)NB * 128 * 4);
    float* M1     = (float*)nxt(80);
    float* M2     = (float*)nxt(32);
    int* cnt      = (int*)nxt((size_t)N_NODES * 4);
    int* pre      = (int*)nxt((size_t)N_NODES * 4);
    int* bsum     = (int*)nxt(64 * 4);
    int* row_ptr  = (int*)nxt((size_t)(N_NODES + 1) * 4);
    int* cursor   = (int*)nxt((size_t)N_NODES * 4);
    u64* epack    = (u64*)nxt((size_t)N_EDGES * 8);
    int* ssrc     = (int*)nxt((size_t)N_EDGES * 4);
    float* a1es   = (float*)nxt((size_t)N_EDGES * 16);
    float* a2es   = (float*)nxt((size_t)N_EDGES * 4);
    float* visbuf = (float*)nxt((size_t)N_NODES * 64 * 4);   // vis, later aliased as w2
    u16* h1       = (u16*)nxt((size_t)N_NODES * 256 * 2);
    u16* out1     = (u16*)nxt((size_t)N_NODES * 256 * 2);
    float* w1buf  = (float*)nxt((size_t)N_EDGES * 16);       // w1, later aliased as h2
    float* hfin   = (float*)nxt((size_t)N_NODES * 64 * 4);
    float* a1s    = (float*)nxt((size_t)N_NODES * 16);
    float* a1d    = (float*)nxt((size_t)N_NODES * 16);
    float* a2s    = (float*)nxt((size_t)N_NODES * 4);
    float* a2d    = (float*)nxt((size_t)N_NODES * 4);

    float* vis = visbuf;
    float* w2  = visbuf;      // vis dead after k_h1; w2 written by k_soft2 (later)
    float* w1  = w1buf;
    float* h2  = w1buf;       // w1 dead after k_gath1; h2 written by k_h2 (later)

    hipMemsetAsync(cnt, 0, (size_t)N_NODES * 4, stream);
    k_prep<<<1, 32, 0, stream>>>(g1We, g1ae, g2We, g2ae, M1, M2);
    k_scene<<<(NB * 128) / 256, 256, 0, stream>>>(gf, sceneW, sceneb, scene);
    k_hist<<<N_EDGES / 256, 256, 0, stream>>>(ei, cnt);
    k_scan_blk<<<64, 256, 0, stream>>>(cnt, pre, bsum);
    k_scan_top<<<1, 64, 0, stream>>>(bsum);
    k_scan_fix<<<N_NODES / 256, 256, 0, stream>>>(pre, bsum, row_ptr, cursor);
    k_scatter<<<N_EDGES / 256, 256, 0, stream>>>(ei, cursor, epack);
    k_payload<<<N_EDGES / 256, 256, 0, stream>>>(epack, ea, M1, M2, ssrc, a1es, a2es);
    k_vis<<<N_NODES / 64, 256, 0, stream>>>(roi, roiW, roib, vis);
    k_h1<<<dim3(N_NODES / 32, 2), 256, 0, stream>>>(x, vis, g1W, h1);
    k_a1<<<N_NODES / 64, 256, 0, stream>>>(h1, g1as, g1ad, a1s, a1d);
    k_soft1<<<N_NODES / 4, 256, 0, stream>>>(row_ptr, ssrc, a1s, a1d, a1es, w1);
    k_gath1<<<N_NODES / 4, 256, 0, stream>>>(row_ptr, ssrc, w1, h1, g1b, out1);
    k_h2<<<N_NODES / 64, 256, 0, stream>>>(out1, g2W, h2);
    k_a2<<<N_NODES / 4, 256, 0, stream>>>(h2, g2as, g2ad, a2s, a2d);
    k_soft2<<<N_NODES / 16, 256, 0, stream>>>(row_ptr, ssrc, a2s, a2d, a2es, w2);
    k_gath2<<<N_NODES / 4, 256, 0, stream>>>(row_ptr, ssrc, w2, h2, g2b, hfin);
    k_pool<<<NB, 64, 0, stream>>>(bvec, hfin, gateW, gateb, scene, c1W, c1b, c2W, c2b, (float*)d_out);
}

// Round 6
// 628.506 us; speedup vs baseline: 1.9405x; 1.1331x over previous
//
#include <hip/hip_runtime.h>

#define N_NODES 65536
#define N_EDGES 1048576
#define NB      512

typedef unsigned short u16;
typedef unsigned int   u32;
typedef unsigned long long u64;

__device__ __forceinline__ float bf2f(u16 u) { return __uint_as_float(((u32)u) << 16); }
__device__ __forceinline__ float lo16(u32 u) { return __uint_as_float(u << 16); }
__device__ __forceinline__ float hi16(u32 u) { return __uint_as_float(u & 0xffff0000u); }
__device__ __forceinline__ u16 f2bf(float f) {
    u32 u = __float_as_uint(f);
    u32 r = (u + 0x7fffu + ((u >> 16) & 1u)) >> 16;
    return (u16)r;
}
__device__ __forceinline__ float wsum(float v) {
    for (int o = 32; o; o >>= 1) v += __shfl_xor(v, o, 64);
    return v;
}
__device__ __forceinline__ float wmax(float v) {
    for (int o = 32; o; o >>= 1) v = fmaxf(v, __shfl_xor(v, o, 64));
    return v;
}

// ---------- tiny precompute ----------
__global__ void k_prep(const float* g1We, const float* g1ae, const float* g2We, const float* g2ae,
                       float* M1, float* M2) {
    int t = threadIdx.x;
    if (t < 20) {
        int j = t >> 2, h = t & 3;
        float s = 0.f;
        for (int c = 0; c < 64; c++) s += g1We[j * 256 + h * 64 + c] * g1ae[h * 64 + c];
        M1[t] = s;
    } else if (t < 25) {
        int j = t - 20;
        float s = 0.f;
        for (int c = 0; c < 64; c++) s += g2We[j * 64 + c] * g2ae[c];
        M2[j] = s;
    }
}

// ---------- scene ----------
__global__ __launch_bounds__(256) void k_scene(const float* __restrict__ gf, const float* __restrict__ W,
                                               const float* __restrict__ bias, float* __restrict__ scene) {
    int idx = blockIdx.x * 256 + threadIdx.x;
    int b = idx >> 7, j = idx & 127;
    float acc = 0.f;
    for (int k = 0; k < 512; k++) acc += gf[b * 512 + k] * W[k * 128 + j];
    scene[idx] = acc + bias[j];
}

// ---------- histogram ----------
__global__ __launch_bounds__(256) void k_hist(const int* ei, int* cnt) {
    int e = blockIdx.x * 256 + threadIdx.x;
    atomicAdd(&cnt[ei[N_EDGES + e]], 1);
}

// ---------- hierarchical exclusive scan ----------
__global__ __launch_bounds__(256) void k_scan_blk(const int* __restrict__ cnt, int* __restrict__ pre,
                                                  int* __restrict__ bsum) {
    __shared__ int sd[256];
    int t = threadIdx.x, b = blockIdx.x;
    int base = b * 1024 + t * 4;
    int4 c = *(const int4*)(cnt + base);
    int s = c.x + c.y + c.z + c.w;
    sd[t] = s;
    __syncthreads();
    for (int off = 1; off < 256; off <<= 1) {
        int v = (t >= off) ? sd[t - off] : 0;
        __syncthreads();
        sd[t] += v;
        __syncthreads();
    }
    int excl = sd[t] - s;
    int4 p;
    p.x = excl;
    p.y = excl + c.x;
    p.z = excl + c.x + c.y;
    p.w = excl + c.x + c.y + c.z;
    *(int4*)(pre + base) = p;
    if (t == 255) bsum[b] = sd[255];
}

__global__ __launch_bounds__(64) void k_scan_top(int* bsum) {
    int t = threadIdx.x;
    int v = bsum[t];
    int inc = v;
    for (int off = 1; off < 64; off <<= 1) {
        int u = __shfl_up(inc, off, 64);
        if (t >= off) inc += u;
    }
    bsum[t] = inc - v;
}

__global__ __launch_bounds__(256) void k_scan_fix(const int* __restrict__ pre, const int* __restrict__ bsum,
                                                  int* __restrict__ row_ptr, int* __restrict__ coarse_cur) {
    int i = blockIdx.x * 256 + threadIdx.x;
    int v = pre[i] + bsum[i >> 10];
    row_ptr[i] = v;
    if ((i & 255) == 0) coarse_cur[i >> 8] = v;
    if (i == 0) row_ptr[N_NODES] = N_EDGES;
}

// ---------- bucket pass: 256 coarse buckets (dst>>8), run-formed coalesced output ----------
__global__ __launch_bounds__(256) void k_bucket(const int* __restrict__ ei, int* coarse_cur,
                                                u32* __restrict__ bpack, int* __restrict__ bsrc) {
    __shared__ u32 stageP[4096];
    __shared__ int stageS[4096];
    __shared__ int bcnt[256], bscan[256], boff[256], gbase[256];
    int t = threadIdx.x;
    int e0 = blockIdx.x * 4096;
    bcnt[t] = 0;
    __syncthreads();
    int dreg[16], sreg[16];
    for (int it = 0; it < 16; it++) {
        int e = e0 + it * 256 + t;
        int dd = ei[N_EDGES + e];
        dreg[it] = dd;
        sreg[it] = ei[e];
        atomicAdd(&bcnt[dd >> 8], 1);
    }
    __syncthreads();
    int v = bcnt[t];
    bscan[t] = v;
    __syncthreads();
    for (int off = 1; off < 256; off <<= 1) {
        int u = (t >= off) ? bscan[t - off] : 0;
        __syncthreads();
        bscan[t] += u;
        __syncthreads();
    }
    boff[t] = bscan[t] - v;                      // exclusive
    gbase[t] = v ? atomicAdd(&coarse_cur[t], v) : 0;
    __syncthreads();
    for (int it = 0; it < 16; it++) {
        int e = e0 + it * 256 + t;
        int b = dreg[it] >> 8;
        int pos = atomicAdd(&boff[b], 1);
        stageP[pos] = ((u32)e << 12) | (u32)(dreg[it] & 255);
        stageS[pos] = sreg[it];
    }
    __syncthreads();
    for (int idx = t; idx < 4096; idx += 256) {
        int lo = 0, hi = 255;
        while (lo < hi) { int mid = (lo + hi) >> 1; if (bscan[mid] > idx) hi = mid; else lo = mid + 1; }
        int b = lo;
        int g = gbase[b] + (idx - (bscan[b] - bcnt[b]));
        bpack[g] = stageP[idx];
        bsrc[g] = stageS[idx];
    }
}

// ---------- local sort within bucket: randomness stays in one block's 16KB window ----------
__global__ __launch_bounds__(256) void k_sortb(const u32* __restrict__ bpack, const int* __restrict__ bsrc,
                                               const int* __restrict__ row_ptr,
                                               int* __restrict__ eord, int* __restrict__ ssrc) {
    __shared__ int cur[256];
    int t = threadIdx.x, b = blockIdx.x;
    int nbase = b * 256;
    cur[t] = row_ptr[nbase + t];
    __syncthreads();
    int beg = row_ptr[nbase];
    int end = row_ptr[nbase + 256];
    for (int i = beg + t; i < end; i += 256) {
        u32 wd = bpack[i];
        int src = bsrc[i];
        int d8 = wd & 255;
        int pos = atomicAdd(&cur[d8], 1);
        eord[pos] = (int)(wd >> 12);
        ssrc[pos] = src;
    }
}

// ---------- payload in pos order ----------
__global__ __launch_bounds__(256) void k_payload(const int* __restrict__ eord, const float* __restrict__ ea,
                                                 const float* __restrict__ M1, const float* __restrict__ M2,
                                                 float* __restrict__ a1es, float* __restrict__ a2es) {
    int pos = blockIdx.x * 256 + threadIdx.x;
    int e = eord[pos];
    float v[5];
    for (int j = 0; j < 5; j++) v[j] = ea[(size_t)e * 5 + j];
    float4 o;
    o.x = v[0]*M1[0]  + v[1]*M1[4]  + v[2]*M1[8]  + v[3]*M1[12] + v[4]*M1[16];
    o.y = v[0]*M1[1]  + v[1]*M1[5]  + v[2]*M1[9]  + v[3]*M1[13] + v[4]*M1[17];
    o.z = v[0]*M1[2]  + v[1]*M1[6]  + v[2]*M1[10] + v[3]*M1[14] + v[4]*M1[18];
    o.w = v[0]*M1[3]  + v[1]*M1[7]  + v[2]*M1[11] + v[3]*M1[15] + v[4]*M1[19];
    *(float4*)(a1es + (size_t)pos * 4) = o;
    a2es[pos] = v[0]*M2[0] + v[1]*M2[1] + v[2]*M2[2] + v[3]*M2[3] + v[4]*M2[4];
}

// ---------- register-blocked GEMM: vis = relu(roi @ roiW + b) ----------
__global__ __launch_bounds__(256) void k_vis(const float* __restrict__ A, const float* __restrict__ W,
                                             const float* __restrict__ bias, float* __restrict__ out) {
    __shared__ float At[64][68];
    __shared__ float Wl[64][68];
    int t = threadIdx.x;
    int n0 = blockIdx.x * 64;
    int cg = t & 15, rg = t >> 4;
    int sr = t >> 2, scs = (t & 3) * 16;
    float acc[4][4];
    for (int i = 0; i < 4; i++) for (int j = 0; j < 4; j++) acc[i][j] = 0.f;
    for (int kc = 0; kc < 4; kc++) {
        __syncthreads();
        const float* ap = A + (size_t)(n0 + sr) * 256 + kc * 64 + scs;
        float4 q0 = *(const float4*)ap, q1 = *(const float4*)(ap + 4);
        float4 q2 = *(const float4*)(ap + 8), q3 = *(const float4*)(ap + 12);
        At[scs + 0][sr] = q0.x;  At[scs + 1][sr] = q0.y;  At[scs + 2][sr] = q0.z;  At[scs + 3][sr] = q0.w;
        At[scs + 4][sr] = q1.x;  At[scs + 5][sr] = q1.y;  At[scs + 6][sr] = q1.z;  At[scs + 7][sr] = q1.w;
        At[scs + 8][sr] = q2.x;  At[scs + 9][sr] = q2.y;  At[scs + 10][sr] = q2.z; At[scs + 11][sr] = q2.w;
        At[scs + 12][sr] = q3.x; At[scs + 13][sr] = q3.y; At[scs + 14][sr] = q3.z; At[scs + 15][sr] = q3.w;
        const float* wp = W + (size_t)(kc * 64 + sr) * 64 + scs;
        *(float4*)&Wl[sr][scs + 0]  = *(const float4*)wp;
        *(float4*)&Wl[sr][scs + 4]  = *(const float4*)(wp + 4);
        *(float4*)&Wl[sr][scs + 8]  = *(const float4*)(wp + 8);
        *(float4*)&Wl[sr][scs + 12] = *(const float4*)(wp + 12);
        __syncthreads();
        for (int k = 0; k < 64; k++) {
            float4 a4 = *(const float4*)&At[k][rg * 4];
            float4 w4 = *(const float4*)&Wl[k][cg * 4];
            acc[0][0] += a4.x * w4.x; acc[0][1] += a4.x * w4.y; acc[0][2] += a4.x * w4.z; acc[0][3] += a4.x * w4.w;
            acc[1][0] += a4.y * w4.x; acc[1][1] += a4.y * w4.y; acc[1][2] += a4.y * w4.z; acc[1][3] += a4.y * w4.w;
            acc[2][0] += a4.z * w4.x; acc[2][1] += a4.z * w4.y; acc[2][2] += a4.z * w4.z; acc[2][3] += a4.z * w4.w;
            acc[3][0] += a4.w * w4.x; acc[3][1] += a4.w * w4.y; acc[3][2] += a4.w * w4.z; acc[3][3] += a4.w * w4.w;
        }
    }
    float4 bb = *(const float4*)(bias + cg * 4);
    for (int i = 0; i < 4; i++) {
        float4 o;
        o.x = fmaxf(acc[i][0] + bb.x, 0.f);
        o.y = fmaxf(acc[i][1] + bb.y, 0.f);
        o.z = fmaxf(acc[i][2] + bb.z, 0.f);
        o.w = fmaxf(acc[i][3] + bb.w, 0.f);
        *(float4*)(out + (size_t)(n0 + rg * 4 + i) * 64 + cg * 4) = o;
    }
}

// ---------- register-blocked GEMM: h2 = out1(bf16) @ g2W ----------
__global__ __launch_bounds__(256) void k_h2(const u16* __restrict__ A, const float* __restrict__ W,
                                            float* __restrict__ out) {
    __shared__ float At[64][68];
    __shared__ float Wl[64][68];
    int t = threadIdx.x;
    int n0 = blockIdx.x * 64;
    int cg = t & 15, rg = t >> 4;
    int sr = t >> 2, scs = (t & 3) * 16;
    float acc[4][4];
    for (int i = 0; i < 4; i++) for (int j = 0; j < 4; j++) acc[i][j] = 0.f;
    for (int kc = 0; kc < 4; kc++) {
        __syncthreads();
        const u16* ap = A + (size_t)(n0 + sr) * 256 + kc * 64 + scs;
        uint4 u0 = *(const uint4*)ap;
        uint4 u1 = *(const uint4*)(ap + 8);
        At[scs + 0][sr] = lo16(u0.x);  At[scs + 1][sr] = hi16(u0.x);
        At[scs + 2][sr] = lo16(u0.y);  At[scs + 3][sr] = hi16(u0.y);
        At[scs + 4][sr] = lo16(u0.z);  At[scs + 5][sr] = hi16(u0.z);
        At[scs + 6][sr] = lo16(u0.w);  At[scs + 7][sr] = hi16(u0.w);
        At[scs + 8][sr] = lo16(u1.x);  At[scs + 9][sr] = hi16(u1.x);
        At[scs + 10][sr] = lo16(u1.y); At[scs + 11][sr] = hi16(u1.y);
        At[scs + 12][sr] = lo16(u1.z); At[scs + 13][sr] = hi16(u1.z);
        At[scs + 14][sr] = lo16(u1.w); At[scs + 15][sr] = hi16(u1.w);
        const float* wp = W + (size_t)(kc * 64 + sr) * 64 + scs;
        *(float4*)&Wl[sr][scs + 0]  = *(const float4*)wp;
        *(float4*)&Wl[sr][scs + 4]  = *(const float4*)(wp + 4);
        *(float4*)&Wl[sr][scs + 8]  = *(const float4*)(wp + 8);
        *(float4*)&Wl[sr][scs + 12] = *(const float4*)(wp + 12);
        __syncthreads();
        for (int k = 0; k < 64; k++) {
            float4 a4 = *(const float4*)&At[k][rg * 4];
            float4 w4 = *(const float4*)&Wl[k][cg * 4];
            acc[0][0] += a4.x * w4.x; acc[0][1] += a4.x * w4.y; acc[0][2] += a4.x * w4.z; acc[0][3] += a4.x * w4.w;
            acc[1][0] += a4.y * w4.x; acc[1][1] += a4.y * w4.y; acc[1][2] += a4.y * w4.z; acc[1][3] += a4.y * w4.w;
            acc[2][0] += a4.z * w4.x; acc[2][1] += a4.z * w4.y; acc[2][2] += a4.z * w4.z; acc[2][3] += a4.z * w4.w;
            acc[3][0] += a4.w * w4.x; acc[3][1] += a4.w * w4.y; acc[3][2] += a4.w * w4.z; acc[3][3] += a4.w * w4.w;
        }
    }
    for (int i = 0; i < 4; i++) {
        float4 o = make_float4(acc[i][0], acc[i][1], acc[i][2], acc[i][3]);
        *(float4*)(out + (size_t)(n0 + rg * 4 + i) * 64 + cg * 4) = o;
    }
}

// ---------- h1 = [x | vis] @ g1_W ----------
__global__ __launch_bounds__(256) void k_h1(const float* __restrict__ x, const float* __restrict__ vis,
                                            const float* __restrict__ g1W, u16* __restrict__ h1) {
    __shared__ float At[77][36];
    __shared__ float Wl[77][132];
    int t = threadIdx.x, ch = blockIdx.y;
    int n0 = blockIdx.x * 32;
    int cg = t & 31, rg = t >> 5;
    for (int idx = t; idx < 9856; idx += 256) {
        int k = idx >> 7, c = idx & 127;
        Wl[k][c] = g1W[(size_t)k * 256 + ch * 128 + c];
    }
    for (int idx = t; idx < 2464; idx += 256) {
        int r = idx / 77, k = idx - r * 77;
        At[k][r] = (k < 13) ? x[(size_t)(n0 + r) * 13 + k] : vis[(size_t)(n0 + r) * 64 + (k - 13)];
    }
    __syncthreads();
    float acc[4][4];
    for (int i = 0; i < 4; i++) for (int j = 0; j < 4; j++) acc[i][j] = 0.f;
    for (int k = 0; k < 77; k++) {
        float4 a4 = *(const float4*)&At[k][rg * 4];
        float4 w4 = *(const float4*)&Wl[k][cg * 4];
        acc[0][0] += a4.x * w4.x; acc[0][1] += a4.x * w4.y; acc[0][2] += a4.x * w4.z; acc[0][3] += a4.x * w4.w;
        acc[1][0] += a4.y * w4.x; acc[1][1] += a4.y * w4.y; acc[1][2] += a4.y * w4.z; acc[1][3] += a4.y * w4.w;
        acc[2][0] += a4.z * w4.x; acc[2][1] += a4.z * w4.y; acc[2][2] += a4.z * w4.z; acc[2][3] += a4.z * w4.w;
        acc[3][0] += a4.w * w4.x; acc[3][1] += a4.w * w4.y; acc[3][2] += a4.w * w4.z; acc[3][3] += a4.w * w4.w;
    }
    for (int i = 0; i < 4; i++) {
        uint2 pk;
        pk.x = (u32)f2bf(acc[i][0]) | ((u32)f2bf(acc[i][1]) << 16);
        pk.y = (u32)f2bf(acc[i][2]) | ((u32)f2bf(acc[i][3]) << 16);
        *(uint2*)(h1 + (size_t)(n0 + rg * 4 + i) * 256 + ch * 128 + cg * 4) = pk;
    }
}

// ---------- a1_s/a1_d ----------
__global__ __launch_bounds__(256) void k_a1(const u16* __restrict__ h1, const float* __restrict__ as_,
                                            const float* __restrict__ ad_, float* a1s, float* a1d) {
    int t = threadIdx.x;
    int w = t >> 6, L = t & 63;
    float4 as4 = *(const float4*)(as_ + 4 * L);
    float4 ad4 = *(const float4*)(ad_ + 4 * L);
    int base = (blockIdx.x * 4 + w) * 16;
    for (int j = 0; j < 16; j++) {
        int n = base + j;
        uint2 u = *((const uint2*)(h1 + (size_t)n * 256) + L);
        float v0 = lo16(u.x), v1 = hi16(u.x), v2 = lo16(u.y), v3 = hi16(u.y);
        float ps = v0 * as4.x + v1 * as4.y + v2 * as4.z + v3 * as4.w;
        float pd = v0 * ad4.x + v1 * ad4.y + v2 * ad4.z + v3 * ad4.w;
        for (int o = 1; o < 16; o <<= 1) { ps += __shfl_xor(ps, o, 64); pd += __shfl_xor(pd, o, 64); }
        if ((L & 15) == 0) {
            a1s[n * 4 + (L >> 4)] = ps;
            a1d[n * 4 + (L >> 4)] = pd;
        }
    }
}

__global__ __launch_bounds__(256) void k_a2(const float* __restrict__ h2, const float* __restrict__ as_,
                                            const float* __restrict__ ad_, float* a2s, float* a2d) {
    int t = threadIdx.x;
    int w = t >> 6, lane = t & 63;
    int n = blockIdx.x * 4 + w;
    float v = h2[(size_t)n * 64 + lane];
    float ps = wsum(v * as_[lane]);
    float pd = wsum(v * ad_[lane]);
    if (lane == 0) { a2s[n] = ps; a2d[n] = pd; }
}

// ---------- GAT1 softmax ----------
__global__ __launch_bounds__(256) void k_soft1(const int* __restrict__ row_ptr, const int* __restrict__ ssrc,
                                               const float* __restrict__ a1s, const float* __restrict__ a1d,
                                               const float* __restrict__ a1es, float* __restrict__ w1) {
    int t = threadIdx.x;
    int wv = t >> 6, L = t & 63;
    int n = blockIdx.x * 4 + wv;
    int h = L >> 4, j = L & 15;
    int beg = row_ptr[n], deg = row_ptr[n + 1] - beg;
    if (deg == 0) return;
    float adn = a1d[n * 4 + h];
    float m = -3.0e38f, s = 0.f;
    for (int i = j; i < deg; i += 16) {
        int pos = beg + i;
        float l = a1s[ssrc[pos] * 4 + h] + adn + a1es[(size_t)pos * 4 + h];
        l = (l > 0.f) ? l : 0.2f * l;
        if (l > m) { s = s * __expf(m - l) + 1.f; m = l; }
        else       { s += __expf(l - m); }
    }
    for (int o = 1; o < 16; o <<= 1) {
        float mo = __shfl_xor(m, o, 64), so = __shfl_xor(s, o, 64);
        float M = fmaxf(m, mo);
        s = s * __expf(m - M) + so * __expf(mo - M);
        m = M;
    }
    float inv = 1.f / (s + 1e-16f);
    for (int i = j; i < deg; i += 16) {
        int pos = beg + i;
        float l = a1s[ssrc[pos] * 4 + h] + adn + a1es[(size_t)pos * 4 + h];
        l = (l > 0.f) ? l : 0.2f * l;
        w1[(size_t)pos * 4 + h] = __expf(l - m) * inv;
    }
}

// ---------- GAT1 gather: wave per node, 4x unroll ----------
__global__ __launch_bounds__(256) void k_gath1(const int* __restrict__ row_ptr, const int* __restrict__ ssrc,
                                               const float* __restrict__ w1, const u16* __restrict__ h1,
                                               const float* __restrict__ bias, u16* __restrict__ out1) {
    int t = threadIdx.x;
    int wv = t >> 6, L = t & 63;
    int n = blockIdx.x * 4 + wv;
    int beg = row_ptr[n], deg = row_ptr[n + 1] - beg;
    int hd = L >> 4;
    float a0 = 0.f, a1v = 0.f, a2v = 0.f, a3v = 0.f;
    int i = 0;
    for (; i + 4 <= deg; i += 4) {
        int p = beg + i;
        int s0 = ssrc[p], s1 = ssrc[p + 1], s2 = ssrc[p + 2], s3 = ssrc[p + 3];
        float wa = w1[(size_t)p * 4 + hd];
        float wb = w1[(size_t)(p + 1) * 4 + hd];
        float wc = w1[(size_t)(p + 2) * 4 + hd];
        float wd = w1[(size_t)(p + 3) * 4 + hd];
        uint2 ua = *((const uint2*)(h1 + (size_t)s0 * 256) + L);
        uint2 ub = *((const uint2*)(h1 + (size_t)s1 * 256) + L);
        uint2 uc = *((const uint2*)(h1 + (size_t)s2 * 256) + L);
        uint2 ud = *((const uint2*)(h1 + (size_t)s3 * 256) + L);
        a0  += wa * lo16(ua.x) + wb * lo16(ub.x) + wc * lo16(uc.x) + wd * lo16(ud.x);
        a1v += wa * hi16(ua.x) + wb * hi16(ub.x) + wc * hi16(uc.x) + wd * hi16(ud.x);
        a2v += wa * lo16(ua.y) + wb * lo16(ub.y) + wc * lo16(uc.y) + wd * lo16(ud.y);
        a3v += wa * hi16(ua.y) + wb * hi16(ub.y) + wc * hi16(uc.y) + wd * hi16(ud.y);
    }
    for (; i < deg; i++) {
        int p0 = beg + i;
        int s0 = ssrc[p0];
        float wa = w1[(size_t)p0 * 4 + hd];
        uint2 ua = *((const uint2*)(h1 + (size_t)s0 * 256) + L);
        a0 += wa * lo16(ua.x); a1v += wa * hi16(ua.x);
        a2v += wa * lo16(ua.y); a3v += wa * hi16(ua.y);
    }
    float4 bb = *(const float4*)(bias + 4 * L);
    uint2 pk;
    pk.x = (u32)f2bf(fmaxf(a0 + bb.x, 0.f)) | ((u32)f2bf(fmaxf(a1v + bb.y, 0.f)) << 16);
    pk.y = (u32)f2bf(fmaxf(a2v + bb.z, 0.f)) | ((u32)f2bf(fmaxf(a3v + bb.w, 0.f)) << 16);
    *((uint2*)(out1 + (size_t)n * 256) + L) = pk;
}

// ---------- GAT2 softmax ----------
__global__ __launch_bounds__(256) void k_soft2(const int* __restrict__ row_ptr, const int* __restrict__ ssrc,
                                               const float* __restrict__ a2s, const float* __restrict__ a2d,
                                               const float* __restrict__ a2es, float* __restrict__ w2) {
    int t = threadIdx.x;
    int wv = t >> 6, L = t & 63;
    int g = L >> 4, j = L & 15;
    int n = blockIdx.x * 16 + wv * 4 + g;
    int beg = row_ptr[n], deg = row_ptr[n + 1] - beg;
    if (deg == 0) return;
    float adn = a2d[n];
    float m = -3.0e38f, s = 0.f;
    for (int i = j; i < deg; i += 16) {
        int pos = beg + i;
        float l = a2s[ssrc[pos]] + adn + a2es[pos];
        l = (l > 0.f) ? l : 0.2f * l;
        if (l > m) { s = s * __expf(m - l) + 1.f; m = l; }
        else       { s += __expf(l - m); }
    }
    for (int o = 1; o < 16; o <<= 1) {
        float mo = __shfl_xor(m, o, 64), so = __shfl_xor(s, o, 64);
        float M = fmaxf(m, mo);
        s = s * __expf(m - M) + so * __expf(mo - M);
        m = M;
    }
    float inv = 1.f / (s + 1e-16f);
    for (int i = j; i < deg; i += 16) {
        int pos = beg + i;
        float l = a2s[ssrc[pos]] + adn + a2es[pos];
        l = (l > 0.f) ? l : 0.2f * l;
        w2[pos] = __expf(l - m) * inv;
    }
}

// ---------- GAT2 gather: 4x unroll ----------
__global__ __launch_bounds__(256) void k_gath2(const int* __restrict__ row_ptr, const int* __restrict__ ssrc,
                                               const float* __restrict__ w2, const float* __restrict__ h2,
                                               const float* __restrict__ bias, float* __restrict__ hfin) {
    int t = threadIdx.x;
    int wv = t >> 6, L = t & 63;
    int n = blockIdx.x * 4 + wv;
    int beg = row_ptr[n], deg = row_ptr[n + 1] - beg;
    float acc = 0.f;
    int i = 0;
    for (; i + 4 <= deg; i += 4) {
        int p = beg + i;
        int s0 = ssrc[p], s1 = ssrc[p + 1], s2 = ssrc[p + 2], s3 = ssrc[p + 3];
        float wa = w2[p], wb = w2[p + 1], wc = w2[p + 2], wd = w2[p + 3];
        float va = h2[(size_t)s0 * 64 + L];
        float vb = h2[(size_t)s1 * 64 + L];
        float vc = h2[(size_t)s2 * 64 + L];
        float vd = h2[(size_t)s3 * 64 + L];
        acc += wa * va + wb * vb + wc * vc + wd * vd;
    }
    for (; i < deg; i++) {
        int p0 = beg + i;
        acc += w2[p0] * h2[(size_t)ssrc[p0] * 64 + L];
    }
    hfin[(size_t)n * 64 + L] = acc + bias[L];
}

// ---------- pooling + classifier ----------
__global__ __launch_bounds__(64) void k_pool(const int* __restrict__ bvec, const float* __restrict__ hf,
                                             const float* gateW, const float* gateb,
                                             const float* __restrict__ scene,
                                             const float* c1W, const float* c1b,
                                             const float* c2W, const float* c2b,
                                             float* __restrict__ outp) {
    int b = blockIdx.x, lane = threadIdx.x;
    __shared__ float gwl[64], se[64], comb[192], hid[64];
    gwl[lane] = gateW[lane];
    __syncthreads();
    int s0, s1;
    { int lo = 0, hi = N_NODES; while (lo < hi) { int mid = (lo + hi) >> 1; if (bvec[mid] < b) lo = mid + 1; else hi = mid; } s0 = lo; }
    { int lo = 0, hi = N_NODES; while (lo < hi) { int mid = (lo + hi) >> 1; if (bvec[mid] < b + 1) lo = mid + 1; else hi = mid; } s1 = lo; }
    float gb = gateb[0];
    float m = -3.0e38f, ssum = 0.f, acc = 0.f;
    for (int cs = s0; cs < s1; cs += 64) {
        int cnt = min(64, s1 - cs);
        float l = -3.0e38f;
        if (lane < cnt) {
            int n = cs + lane;
            float d = 0.f;
            for (int i = 0; i < 64; i++) d += hf[(size_t)n * 64 + i] * gwl[i];
            l = d + gb;
        }
        float cm = wmax(l);
        float newm = fmaxf(m, cm);
        float rsc = __expf(m - newm);
        float e = (lane < cnt) ? __expf(l - newm) : 0.f;
        float es = wsum(e);
        ssum = ssum * rsc + es;
        se[lane] = e;
        __syncthreads();
        float a2 = 0.f;
        for (int i = 0; i < cnt; i++) a2 += se[i] * hf[(size_t)(cs + i) * 64 + lane];
        acc = acc * rsc + a2;
        __syncthreads();
        m = newm;
    }
    float rel = acc / (ssum + 1e-16f);
    comb[lane] = scene[b * 128 + lane];
    comb[64 + lane] = scene[b * 128 + 64 + lane];
    comb[128 + lane] = rel;
    __syncthreads();
    float hj = 0.f;
    for (int k = 0; k < 192; k++) hj += comb[k] * c1W[k * 64 + lane];
    hj += c1b[lane];
    hid[lane] = fmaxf(hj, 0.f);
    __syncthreads();
    if (lane < 3) {
        float o = 0.f;
        for (int k = 0; k < 64; k++) o += hid[k] * c2W[k * 3 + lane];
        o += c2b[lane];
        outp[b * 3 + lane] = o;
    }
}

extern "C" void kernel_launch(void* const* d_in, const int* in_sizes, int n_in,
                              void* d_out, int out_size, void* d_ws, size_t ws_size,
                              hipStream_t stream) {
    (void)in_sizes; (void)n_in; (void)out_size; (void)ws_size;
    const float* gf     = (const float*)d_in[0];
    const float* x      = (const float*)d_in[1];
    const float* roi    = (const float*)d_in[2];
    const int*   ei     = (const int*)d_in[3];
    const float* ea     = (const float*)d_in[4];
    const int*   bvec   = (const int*)d_in[5];
    const float* roiW   = (const float*)d_in[6];
    const float* roib   = (const float*)d_in[7];
    const float* sceneW = (const float*)d_in[8];
    const float* sceneb = (const float*)d_in[9];
    const float* g1W    = (const float*)d_in[10];
    const float* g1as   = (const float*)d_in[11];
    const float* g1ad   = (const float*)d_in[12];
    const float* g1We   = (const float*)d_in[13];
    const float* g1ae   = (const float*)d_in[14];
    const float* g1b    = (const float*)d_in[15];
    const float* g2W    = (const float*)d_in[16];
    const float* g2as   = (const float*)d_in[17];
    const float* g2ad   = (const float*)d_in[18];
    const float* g2We   = (const float*)d_in[19];
    const float* g2ae   = (const float*)d_in[20];
    const float* g2b    = (const float*)d_in[21];
    const float* gateW  = (const float*)d_in[22];
    const float* gateb  = (const float*)d_in[23];
    const float* c1W    = (const float*)d_in[24];
    const float* c1b    = (const float*)d_in[25];
    const float* c2W    = (const float*)d_in[26];
    const float* c2b    = (const float*)d_in[27];

    char* w = (char*)d_ws;
    size_t o = 0;
    auto nxt = [&](size_t bytes) -> char* {
        char* p = w + o;
        o += (bytes + 255) & ~(size_t)255;
        return p;
    };
    float* scene  = (float*)nxt((size_t)NB * 128 * 4);
    float* M1     = (float*)nxt(80);
    float* M2     = (float*)nxt(32);
    int* cnt      = (int*)nxt((size_t)N_NODES * 4);
    int* pre      = (int*)nxt((size_t)N_NODES * 4);
    int* bsum     = (int*)nxt(64 * 4);
    int* row_ptr  = (int*)nxt((size_t)(N_NODES + 1) * 4);
    int* coarse   = (int*)nxt(256 * 4);
    u32* bpack    = (u32*)nxt((size_t)N_EDGES * 4);
    int* bsrc     = (int*)nxt((size_t)N_EDGES * 4);
    int* eord     = (int*)nxt((size_t)N_EDGES * 4);
    int* ssrc     = (int*)nxt((size_t)N_EDGES * 4);
    float* a1es   = (float*)nxt((size_t)N_EDGES * 16);
    float* a2es   = (float*)nxt((size_t)N_EDGES * 4);
    float* visbuf = (float*)nxt((size_t)N_NODES * 64 * 4);   // vis, later aliased as w2
    u16* h1       = (u16*)nxt((size_t)N_NODES * 256 * 2);
    u16* out1     = (u16*)nxt((size_t)N_NODES * 256 * 2);
    float* w1buf  = (float*)nxt((size_t)N_EDGES * 16);       // w1, later aliased as h2
    float* hfin   = (float*)nxt((size_t)N_NODES * 64 * 4);
    float* a1s    = (float*)nxt((size_t)N_NODES * 16);
    float* a1d    = (float*)nxt((size_t)N_NODES * 16);
    float* a2s    = (float*)nxt((size_t)N_NODES * 4);
    float* a2d    = (float*)nxt((size_t)N_NODES * 4);

    float* vis = visbuf;
    float* w2  = visbuf;      // vis dead after k_h1; w2 written by k_soft2 (later)
    float* w1  = w1buf;
    float* h2  = w1buf;       // w1 dead after k_gath1; h2 written by k_h2 (later)

    hipMemsetAsync(cnt, 0, (size_t)N_NODES * 4, stream);
    k_prep<<<1, 32, 0, stream>>>(g1We, g1ae, g2We, g2ae, M1, M2);
    k_scene<<<(NB * 128) / 256, 256, 0, stream>>>(gf, sceneW, sceneb, scene);
    k_hist<<<N_EDGES / 256, 256, 0, stream>>>(ei, cnt);
    k_scan_blk<<<64, 256, 0, stream>>>(cnt, pre, bsum);
    k_scan_top<<<1, 64, 0, stream>>>(bsum);
    k_scan_fix<<<N_NODES / 256, 256, 0, stream>>>(pre, bsum, row_ptr, coarse);
    k_bucket<<<256, 256, 0, stream>>>(ei, coarse, bpack, bsrc);
    k_sortb<<<256, 256, 0, stream>>>(bpack, bsrc, row_ptr, eord, ssrc);
    k_payload<<<N_EDGES / 256, 256, 0, stream>>>(eord, ea, M1, M2, a1es, a2es);
    k_vis<<<N_NODES / 64, 256, 0, stream>>>(roi, roiW, roib, vis);
    k_h1<<<dim3(N_NODES / 32, 2), 256, 0, stream>>>(x, vis, g1W, h1);
    k_a1<<<N_NODES / 64, 256, 0, stream>>>(h1, g1as, g1ad, a1s, a1d);
    k_soft1<<<N_NODES / 4, 256, 0, stream>>>(row_ptr, ssrc, a1s, a1d, a1es, w1);
    k_gath1<<<N_NODES / 4, 256, 0, stream>>>(row_ptr, ssrc, w1, h1, g1b, out1);
    k_h2<<<N_NODES / 64, 256, 0, stream>>>(out1, g2W, h2);
    k_a2<<<N_NODES / 4, 256, 0, stream>>>(h2, g2as, g2ad, a2s, a2d);
    k_soft2<<<N_NODES / 16, 256, 0, stream>>>(row_ptr, ssrc, a2s, a2d, a2es, w2);
    k_gath2<<<N_NODES / 4, 256, 0, stream>>>(row_ptr, ssrc, w2, h2, g2b, hfin);
    k_pool<<<NB, 64, 0, stream>>>(bvec, hfin, gateW, gateb, scene, c1W, c1b, c2W, c2b, (float*)d_out);
}